// Round 6
// baseline (744.841 us; speedup 1.0000x reference)
//
#include <hip/hip_runtime.h>

typedef unsigned short u16;
using f32x4  = __attribute__((ext_vector_type(4))) float;
using bf16x8 = __attribute__((ext_vector_type(8))) __bf16;

#define Bz   64
#define Nn   197
#define Dd   768
#define Hh   12
#define HDp  64
#define MLPD 3072
#define ROWS (Bz*Nn)        /* 12608 */
#define NM   (Nn*Nn)        /* 38809 */
#define NPAD 224

// fixed region offsets (bytes)
#define OFF_H    0UL            /* hbuf bf16 12608x768 : 19,365,888 */
#define OFF_X1   19365888UL     /* x1   f32  12608x768 : 38,731,776 */
#define OFF_BIA  58097664UL     /* bias f32  12x197x197:  1,862,832 */
#define OFF_WB   59960496UL     /* bf16 weights        : 14,155,776 */
#define OFF_CH   74116272UL     /* chunked region */
// bf16 weight sub-offsets (elements)
#define WQKV_E 0UL
#define WPRJ_E 1769472UL
#define WFC1_E 2359296UL
#define WFC2_E 4718592UL
// per-batch chunk strides (bytes)
#define QKV_B  907776UL
#define P_B    1059072UL
#define VT_B   344064UL
#define CHUNK_B 2310912UL

__device__ inline float b2f(u16 v){ unsigned u = ((unsigned)v) << 16; float f; __builtin_memcpy(&f,&u,4); return f; }
__device__ inline u16 f2b(float f){ unsigned u; __builtin_memcpy(&u,&f,4); u += 0x7FFFu + ((u>>16)&1u); return (u16)(u>>16); }

// fast gelu: Abramowitz-Stegun 7.1.26 erf approx, |err(erf)| <= 1.5e-7
__device__ inline float gelu_f(float x){
    float z  = fabsf(x) * 0.70710678118f;
    float t  = 1.f / (1.f + 0.3275911f * z);
    float y  = t*(0.254829592f + t*(-0.284496736f + t*(1.421413741f + t*(-1.453152027f + t*1.061405429f))));
    float er = 1.f - y * __expf(-z*z);
    er = copysignf(er, x);
    return 0.5f * x * (1.f + er);
}

__device__ inline void gload_lds16(const u16* g, u16* l) {
    __builtin_amdgcn_global_load_lds((const __attribute__((address_space(1))) void*)g,
                                     (__attribute__((address_space(3))) void*)l, 16, 0, 0);
}

// ---------------- f32 -> bf16 convert (weights staging) ----------------
__global__ __launch_bounds__(256)
void conv_b16(const float* __restrict__ src, u16* __restrict__ dst, int n4)
{
    int t = blockIdx.x*256 + threadIdx.x;
    if (t >= n4) return;
    float4 v = *(const float4*)(src + (size_t)t*4);
    u16* d = dst + (size_t)t*4;
    d[0] = f2b(v.x); d[1] = f2b(v.y); d[2] = f2b(v.z); d[3] = f2b(v.w);
}

// ======== 256x256 NT GEMM, 8 waves, BK=64, FULL-TILE prefetch cover ========
// Schedule v3: all 8 staging loads of tile t+1 issued at START of iter t
// (after vmcnt(4) confirms s0(t) landed & buf p^1 is consumed). MID wait
// vmcnt(8) confirms s1(t) while keeping all of t+1 in flight -> cover = 1 full
// K-tile (~1400+ cyc) > worst-case HBM latency (~900). Never vmcnt(0) in loop.
// Epilogue v2 with padded LDS C-tile strides (bank-conflict fix).
// EPI: 0=qkv  4=fc1+gelu  5=fc2->out(f32, fused residual)
template<int EPI>
__global__ __launch_bounds__(512, 1)
void gemm256v(const u16* __restrict__ A, const u16* __restrict__ W, void* __restrict__ Cp,
              int M, int N, int K, int lda, int ldw,
              const float* __restrict__ e0, const float* __restrict__ e1,
              const float* __restrict__ e2, const float* __restrict__ e3,
              const float* __restrict__ ef)
{
    extern __shared__ u16 lds[];
    constexpr int SWEEP = 4096;             // elems per gload sweep (512 thr x 8)
    constexpr int ICA  = 2;
    constexpr int ICB  = 2;
    constexpr int ASZ  = 256 * 32;          // 8192 elems per k-slice chunk
    constexpr int BSZ  = 256 * 32;
    constexpr int ABUF = 2 * ASZ;
    constexpr int BBUF = 2 * BSZ;
    constexpr int MF   = 8;                 // m-frags per wave (128 rows)
    constexpr int MH   = 4;

    u16* sA = lds;
    u16* sB = lds + 2 * ABUF;

    const int tid  = threadIdx.x;
    const int lane = tid & 63;
    const int wave = tid >> 6;
    const int wr   = wave >> 2;             // 0..1
    const int wc   = wave & 3;              // 0..3
    const int rid  = lane & 15;
    const int kg   = lane >> 4;
    const int m0   = blockIdx.y * 256;
    const int n0   = blockIdx.x * 256;
    const int t8   = tid * 8;

    const u16* asrc[2][ICA]; int adst[2][ICA];
    const u16* bsrc[2][ICB]; int bdst[2][ICB];
#pragma unroll
    for (int s = 0; s < 2; ++s) {
#pragma unroll
        for (int i = 0; i < ICA; ++i) {
            int e = i*SWEEP + t8, r = e >> 5;
            int g = ((e >> 3) & 3) ^ ((r >> 1) & 3);
            int row = m0 + r; if (row > M-1) row = M-1;
            asrc[s][i] = A + (size_t)row*lda + s*32 + g*8;
            adst[s][i] = s*ASZ + e;
        }
#pragma unroll
        for (int i = 0; i < ICB; ++i) {
            int e = i*SWEEP + t8, r = e >> 5;
            int g = ((e >> 3) & 3) ^ ((r >> 1) & 3);
            int col = n0 + r; if (col > N-1) col = N-1;
            bsrc[s][i] = W + (size_t)col*ldw + s*32 + g*8;
            bdst[s][i] = s*BSZ + e;
        }
    }

    const int koA   = (kg ^ ((rid >> 1) & 3)) * 8;
    const int aRow0 = (wr*128 + rid) * 32 + koA;
    const int bRow  = (wc*64  + rid) * 32 + koA;

    f32x4 acc[MF][4];
#pragma unroll
    for (int i = 0; i < MF; ++i)
#pragma unroll
        for (int j = 0; j < 4; ++j) acc[i][j] = (f32x4){0.f,0.f,0.f,0.f};

    // ---- prologue: stage tile 0 into buf 0 (order pinned: s0{A,B} | s1{A,B}) ----
#pragma unroll
    for (int i = 0; i < ICA; ++i) gload_lds16(asrc[0][i], sA + adst[0][i]);
#pragma unroll
    for (int i = 0; i < ICB; ++i) gload_lds16(bsrc[0][i], sB + bdst[0][i]);
    asm volatile("" ::: "memory");
#pragma unroll
    for (int i = 0; i < ICA; ++i) gload_lds16(asrc[1][i], sA + adst[1][i]);
#pragma unroll
    for (int i = 0; i < ICB; ++i) gload_lds16(bsrc[1][i], sB + bdst[1][i]);

    const int NT = K >> 6;
    for (int t = 0; t < NT; ++t) {
        const int p  = t & 1;
        const size_t kpre = (size_t)(t + 1) * 64;
        const u16* paB = sA + p * ABUF;
        const u16* pbB = sB + p * BBUF;
        const int  qa  = (p ^ 1) * ABUF;
        const int  qb  = (p ^ 1) * BBUF;
        bf16x8 af[MH], wf[4];

        // START: s0(t) landed (oldest 4 of 8); all waves done reading buf p^1
        asm volatile("s_waitcnt vmcnt(4) lgkmcnt(0)\n\ts_barrier" ::: "memory");
        // issue ALL of tile t+1 into buf p^1 (full-tile latency cover; garbage-safe at t=NT-1)
#pragma unroll
        for (int i = 0; i < ICA; ++i) gload_lds16(asrc[0][i] + kpre, sA + adst[0][i] + qa);
#pragma unroll
        for (int i = 0; i < ICB; ++i) gload_lds16(bsrc[0][i] + kpre, sB + bdst[0][i] + qb);
        asm volatile("" ::: "memory");   // pin s0-before-s1 issue order
#pragma unroll
        for (int i = 0; i < ICA; ++i) gload_lds16(asrc[1][i] + kpre, sA + adst[1][i] + qa);
#pragma unroll
        for (int i = 0; i < ICB; ++i) gload_lds16(bsrc[1][i] + kpre, sB + bdst[1][i] + qb);

        {   // phase 0: slice 0, m-half 0
            const u16* pa = paB + aRow0;
#pragma unroll
            for (int f = 0; f < MH; ++f) af[f] = *(const bf16x8*)(pa + f*512);
            const u16* pb = pbB + bRow;
#pragma unroll
            for (int j = 0; j < 4; ++j) wf[j] = *(const bf16x8*)(pb + j*512);
            __builtin_amdgcn_s_setprio(1);
#pragma unroll
            for (int f = 0; f < MH; ++f)
#pragma unroll
                for (int j = 0; j < 4; ++j)
                    acc[f][j] = __builtin_amdgcn_mfma_f32_16x16x32_bf16(af[f], wf[j], acc[f][j], 0, 0, 0);
            __builtin_amdgcn_s_setprio(0);
        }
        {   // phase 1: slice 0, m-half 1 (reuses wf)
            const u16* pa = paB + aRow0 + MH*512;
#pragma unroll
            for (int f = 0; f < MH; ++f) af[f] = *(const bf16x8*)(pa + f*512);
            __builtin_amdgcn_s_setprio(1);
#pragma unroll
            for (int f = 0; f < MH; ++f)
#pragma unroll
                for (int j = 0; j < 4; ++j)
                    acc[MH+f][j] = __builtin_amdgcn_mfma_f32_16x16x32_bf16(af[f], wf[j], acc[MH+f][j], 0, 0, 0);
            __builtin_amdgcn_s_setprio(0);
        }
        // MID: s1(t) landed (oldest 4 of 12; all 8 of t+1 stay in flight)
        asm volatile("s_waitcnt vmcnt(8) lgkmcnt(0)\n\ts_barrier" ::: "memory");
        {   // phase 2: slice 1, m-half 0
            const u16* pa = paB + ASZ + aRow0;
#pragma unroll
            for (int f = 0; f < MH; ++f) af[f] = *(const bf16x8*)(pa + f*512);
            const u16* pb = pbB + BSZ + bRow;
#pragma unroll
            for (int j = 0; j < 4; ++j) wf[j] = *(const bf16x8*)(pb + j*512);
            __builtin_amdgcn_s_setprio(1);
#pragma unroll
            for (int f = 0; f < MH; ++f)
#pragma unroll
                for (int j = 0; j < 4; ++j)
                    acc[f][j] = __builtin_amdgcn_mfma_f32_16x16x32_bf16(af[f], wf[j], acc[f][j], 0, 0, 0);
            __builtin_amdgcn_s_setprio(0);
        }
        {   // phase 3: slice 1, m-half 1
            const u16* pa = paB + ASZ + aRow0 + MH*512;
#pragma unroll
            for (int f = 0; f < MH; ++f) af[f] = *(const bf16x8*)(pa + f*512);
            __builtin_amdgcn_s_setprio(1);
#pragma unroll
            for (int f = 0; f < MH; ++f)
#pragma unroll
                for (int j = 0; j < 4; ++j)
                    acc[MH+f][j] = __builtin_amdgcn_mfma_f32_16x16x32_bf16(af[f], wf[j], acc[MH+f][j], 0, 0, 0);
            __builtin_amdgcn_s_setprio(0);
        }
    }
    asm volatile("s_waitcnt vmcnt(0)" ::: "memory");
    __syncthreads();

    // ---- epilogue v2 (8-wave geometry, padded LDS strides) ----
    float* ka = (float*)lds;
    float* kb = ka + 256;
    if (tid < 256) {
        int gn = n0 + tid;
        if constexpr (EPI == 0) {
            float mql = (gn < 768) ? 0.125f : 1.f;
            float bias = 0.f;
            if (gn < 768) bias = e0[gn];
            else if (gn >= 1536) bias = e1[gn-1536];
            float sc = e2[gn];
            ka[tid] = sc * mql;
            kb[tid] = (bias * sc + e3[gn]) * mql;
        } else if constexpr (EPI == 4) {
            ka[tid] = 0.f;
            kb[tid] = e0[gn];
        } else {
            float sc = e1[gn];
            ka[tid] = sc;
            kb[tid] = e0[gn]*sc + e2[gn];
        }
    }
    __syncthreads();
    const int rq = (lane >> 4) * 4;
    const int cc = lane & 15;
    float kaj[4], kbj[4];
#pragma unroll
    for (int j = 0; j < 4; ++j) {
        int c = wc*64 + j*16 + cc;
        kaj[j] = ka[c]; kbj[j] = kb[c];
    }
    __syncthreads();   // done reading coeffs; LDS now reusable as C-tile

    if constexpr (EPI == 0 || EPI == 4) {
        // bf16 output: 256 x (264-padded) u16 tile (135 KB; pad kills 4-way write conflicts)
        u16* ct = lds;
#pragma unroll
        for (int i = 0; i < MF; ++i) {
#pragma unroll
            for (int j = 0; j < 4; ++j) {
#pragma unroll
                for (int r = 0; r < 4; ++r) {
                    int rowL = wr*128 + i*16 + rq + r;
                    int col  = wc*64 + j*16 + cc;
                    float v = acc[i][j][r];
                    u16 o;
                    if constexpr (EPI == 0) o = f2b(v*kaj[j] + kbj[j]);
                    else                    o = f2b(gelu_f(v + kbj[j]));
                    ct[rowL*264 + col] = o;
                }
            }
        }
        __syncthreads();
        constexpr int ldc = (EPI == 0) ? 2304 : 3072;
        u16* C = (u16*)Cp;
#pragma unroll
        for (int sw = 0; sw < 16; ++sw) {
            int rowL = sw*16 + (tid >> 5);
            int gm = m0 + rowL;
            if (gm < M) {
                int col0 = (tid & 31) * 8;
                *(uint4*)(C + (size_t)gm*ldc + n0 + col0) =
                    *(const uint4*)(ct + rowL*264 + col0);
            }
        }
    } else {
        // f32 output with fused residual: two 128 x (260-padded) f32 half-tiles
        float* cf = (float*)lds;
        float* C = (float*)Cp;
#pragma unroll
        for (int h = 0; h < 2; ++h) {
            if (wr == h) {
#pragma unroll
                for (int i = 0; i < MF; ++i) {
#pragma unroll
                    for (int j = 0; j < 4; ++j) {
#pragma unroll
                        for (int r = 0; r < 4; ++r) {
                            int rowH = i*16 + rq + r;
                            int col  = wc*64 + j*16 + cc;
                            cf[rowH*260 + col] = acc[i][j][r]*kaj[j] + kbj[j];
                        }
                    }
                }
            }
            __syncthreads();
#pragma unroll
            for (int sw = 0; sw < 16; ++sw) {
                int rowH = sw*8 + (tid >> 6);
                int gm = m0 + h*128 + rowH;
                if (gm < M) {
                    int col0 = (tid & 63) * 4;
                    f32x4 v  = *(const f32x4*)(cf + rowH*260 + col0);
                    size_t gidx = (size_t)gm*768 + n0 + col0;
                    f32x4 xv = *(const f32x4*)(ef + gidx);
                    f32x4 g3 = *(const f32x4*)(e3 + n0 + col0);
                    f32x4 o;
#pragma unroll
                    for (int q = 0; q < 4; ++q) o[q] = xv[q] + g3[q]*v[q];
                    *(f32x4*)(C + gidx) = o;
                }
            }
            __syncthreads();
        }
    }
}

// ======== 128x128 NT GEMM, 2 blocks/CU, full-tile prefetch cover (proj) ========
// EPI: 3=proj->x1(f32, fused residual)
template<int EPI>
__global__ __launch_bounds__(256, 2)
void gemm128p(const u16* __restrict__ A, const u16* __restrict__ W, void* __restrict__ Cp,
              int M, int N, int K, int lda, int ldw,
              const float* __restrict__ e0, const float* __restrict__ e1,
              const float* __restrict__ e2, const float* __restrict__ e3,
              const float* __restrict__ e4, const float* __restrict__ ef)
{
    extern __shared__ u16 lds[];
    constexpr int SWEEP = 2048;
    constexpr int ICA  = 2;
    constexpr int ICB  = 2;
    constexpr int ASZ  = 128 * 32;
    constexpr int BSZ  = 128 * 32;
    constexpr int ABUF = 2 * ASZ;
    constexpr int BBUF = 2 * BSZ;
    constexpr int MF   = 4;
    constexpr int MH   = 2;

    u16* sA = lds;
    u16* sB = lds + 2 * ABUF;

    const int tid  = threadIdx.x;
    const int lane = tid & 63;
    const int wave = tid >> 6;
    const int wr   = wave >> 1;
    const int wc   = wave & 1;
    const int rid  = lane & 15;
    const int kg   = lane >> 4;
    const int m0   = blockIdx.y * 128;
    const int n0   = blockIdx.x * 128;
    const int t8   = tid * 8;

    const u16* asrc[2][ICA]; int adst[2][ICA];
    const u16* bsrc[2][ICB]; int bdst[2][ICB];
#pragma unroll
    for (int s = 0; s < 2; ++s) {
#pragma unroll
        for (int i = 0; i < ICA; ++i) {
            int e = i*SWEEP + t8, r = e >> 5;
            int g = ((e >> 3) & 3) ^ ((r >> 1) & 3);
            int row = m0 + r; if (row > M-1) row = M-1;
            asrc[s][i] = A + (size_t)row*lda + s*32 + g*8;
            adst[s][i] = s*ASZ + e;
        }
#pragma unroll
        for (int i = 0; i < ICB; ++i) {
            int e = i*SWEEP + t8, r = e >> 5;
            int g = ((e >> 3) & 3) ^ ((r >> 1) & 3);
            int col = n0 + r; if (col > N-1) col = N-1;
            bsrc[s][i] = W + (size_t)col*ldw + s*32 + g*8;
            bdst[s][i] = s*BSZ + e;
        }
    }

    const int koA   = (kg ^ ((rid >> 1) & 3)) * 8;
    const int aRow0 = (wr*64 + rid) * 32 + koA;
    const int bRow  = (wc*64 + rid) * 32 + koA;

    f32x4 acc[MF][4];
#pragma unroll
    for (int i = 0; i < MF; ++i)
#pragma unroll
        for (int j = 0; j < 4; ++j) acc[i][j] = (f32x4){0.f,0.f,0.f,0.f};

    // prologue: tile 0 into buf 0
#pragma unroll
    for (int i = 0; i < ICA; ++i) gload_lds16(asrc[0][i], sA + adst[0][i]);
#pragma unroll
    for (int i = 0; i < ICB; ++i) gload_lds16(bsrc[0][i], sB + bdst[0][i]);
    asm volatile("" ::: "memory");
#pragma unroll
    for (int i = 0; i < ICA; ++i) gload_lds16(asrc[1][i], sA + adst[1][i]);
#pragma unroll
    for (int i = 0; i < ICB; ++i) gload_lds16(bsrc[1][i], sB + bdst[1][i]);

    const int NT = K >> 6;
    for (int t = 0; t < NT; ++t) {
        const int p  = t & 1;
        const size_t kpre = (size_t)(t + 1) * 64;
        const u16* paB = sA + p * ABUF;
        const u16* pbB = sB + p * BBUF;
        const int  qa  = (p ^ 1) * ABUF;
        const int  qb  = (p ^ 1) * BBUF;
        bf16x8 af[MH], wf[4];

        asm volatile("s_waitcnt vmcnt(4) lgkmcnt(0)\n\ts_barrier" ::: "memory");
#pragma unroll
        for (int i = 0; i < ICA; ++i) gload_lds16(asrc[0][i] + kpre, sA + adst[0][i] + qa);
#pragma unroll
        for (int i = 0; i < ICB; ++i) gload_lds16(bsrc[0][i] + kpre, sB + bdst[0][i] + qb);
        asm volatile("" ::: "memory");
#pragma unroll
        for (int i = 0; i < ICA; ++i) gload_lds16(asrc[1][i] + kpre, sA + adst[1][i] + qa);
#pragma unroll
        for (int i = 0; i < ICB; ++i) gload_lds16(bsrc[1][i] + kpre, sB + bdst[1][i] + qb);

        {
            const u16* pa = paB + aRow0;
#pragma unroll
            for (int f = 0; f < MH; ++f) af[f] = *(const bf16x8*)(pa + f*512);
            const u16* pb = pbB + bRow;
#pragma unroll
            for (int j = 0; j < 4; ++j) wf[j] = *(const bf16x8*)(pb + j*512);
            __builtin_amdgcn_s_setprio(1);
#pragma unroll
            for (int f = 0; f < MH; ++f)
#pragma unroll
                for (int j = 0; j < 4; ++j)
                    acc[f][j] = __builtin_amdgcn_mfma_f32_16x16x32_bf16(af[f], wf[j], acc[f][j], 0, 0, 0);
            __builtin_amdgcn_s_setprio(0);
        }
        {
            const u16* pa = paB + aRow0 + MH*512;
#pragma unroll
            for (int f = 0; f < MH; ++f) af[f] = *(const bf16x8*)(pa + f*512);
            __builtin_amdgcn_s_setprio(1);
#pragma unroll
            for (int f = 0; f < MH; ++f)
#pragma unroll
                for (int j = 0; j < 4; ++j)
                    acc[MH+f][j] = __builtin_amdgcn_mfma_f32_16x16x32_bf16(af[f], wf[j], acc[MH+f][j], 0, 0, 0);
            __builtin_amdgcn_s_setprio(0);
        }
        asm volatile("s_waitcnt vmcnt(8) lgkmcnt(0)\n\ts_barrier" ::: "memory");
        {
            const u16* pa = paB + ASZ + aRow0;
#pragma unroll
            for (int f = 0; f < MH; ++f) af[f] = *(const bf16x8*)(pa + f*512);
            const u16* pb = pbB + BSZ + bRow;
#pragma unroll
            for (int j = 0; j < 4; ++j) wf[j] = *(const bf16x8*)(pb + j*512);
            __builtin_amdgcn_s_setprio(1);
#pragma unroll
            for (int f = 0; f < MH; ++f)
#pragma unroll
                for (int j = 0; j < 4; ++j)
                    acc[f][j] = __builtin_amdgcn_mfma_f32_16x16x32_bf16(af[f], wf[j], acc[f][j], 0, 0, 0);
            __builtin_amdgcn_s_setprio(0);
        }
        {
            const u16* pa = paB + ASZ + aRow0 + MH*512;
#pragma unroll
            for (int f = 0; f < MH; ++f) af[f] = *(const bf16x8*)(pa + f*512);
            __builtin_amdgcn_s_setprio(1);
#pragma unroll
            for (int f = 0; f < MH; ++f)
#pragma unroll
                for (int j = 0; j < 4; ++j)
                    acc[MH+f][j] = __builtin_amdgcn_mfma_f32_16x16x32_bf16(af[f], wf[j], acc[MH+f][j], 0, 0, 0);
            __builtin_amdgcn_s_setprio(0);
        }
    }
    asm volatile("s_waitcnt vmcnt(0)" ::: "memory");
    __syncthreads();

    // ---- epilogue v2 (proj: f32 + residual, padded stride 132) ----
    float* ka = (float*)lds;
    float* kb = ka + 128;
    if (tid < 128) {
        int gn = n0 + tid;
        float sc = e1[gn];
        ka[tid] = sc;
        kb[tid] = e0[gn]*sc + e2[gn];
    }
    __syncthreads();
    const int rq = (lane >> 4) * 4;
    const int cc = lane & 15;
    float kaj[4], kbj[4];
#pragma unroll
    for (int j = 0; j < 4; ++j) {
        int c = wc*64 + j*16 + cc;
        kaj[j] = ka[c]; kbj[j] = kb[c];
    }
    __syncthreads();

    float* cf = (float*)lds;
    const float* RES = e4;
    float* C = (float*)Cp;
#pragma unroll
    for (int h = 0; h < 2; ++h) {
        if (wr == h) {
#pragma unroll
            for (int i = 0; i < MF; ++i) {
#pragma unroll
                for (int j = 0; j < 4; ++j) {
#pragma unroll
                    for (int r = 0; r < 4; ++r) {
                        int rowH = i*16 + rq + r;
                        int col  = wc*64 + j*16 + cc;
                        cf[rowH*132 + col] = acc[i][j][r]*kaj[j] + kbj[j];
                    }
                }
            }
        }
        __syncthreads();
#pragma unroll
        for (int sw = 0; sw < 8; ++sw) {
            int rowH = sw*8 + (tid >> 5);
            int gm = m0 + h*64 + rowH;
            if (gm < M) {
                int col0 = (tid & 31) * 4;
                f32x4 v  = *(const f32x4*)(cf + rowH*132 + col0);
                size_t gidx = (size_t)gm*768 + n0 + col0;
                f32x4 xv = *(const f32x4*)(RES + gidx);
                f32x4 g3 = *(const f32x4*)(e3 + n0 + col0);
                f32x4 o;
#pragma unroll
                for (int q = 0; q < 4; ++q) o[q] = xv[q] + g3[q]*v[q];
                *(f32x4*)(C + gidx) = o;
            }
        }
        __syncthreads();
    }
}

// ======== direct-load NT GEMM for small-K attention GEMMs ========
// EPI: 1=scores (f32 tile staged, bias fused in coalesced sweep)
//      2=pv->y  (u16 tile staged, vectorized stores)
template<int EPI>
__global__ __launch_bounds__(256)
void gemm_nt(const u16* __restrict__ A, const u16* __restrict__ W, void* __restrict__ Cp,
             int M, int N, int K, int lda, int ldw, int b0,
             const float* __restrict__ ef)
{
    __shared__ __align__(16) u16 csm[(EPI == 1) ? 32768 : 16384];
    const int tid  = threadIdx.x;
    const int lane = tid & 63;
    const int wave = tid >> 6;
    const int z    = blockIdx.z;
    const int m0   = wave*64;              // grid.y == 1 always (M=197)
    const int n0   = blockIdx.x*64;
    const int rid  = lane & 15;
    const int kq   = (lane >> 4) * 8;

    const u16* Ab = A;
    const u16* Wb = W;
    if constexpr (EPI == 1) {
        int bb = z/12, hh = z - bb*12;
        Ab = A + ((size_t)bb*Nn)*2304 + hh*64;          // q (already *0.125)
        Wb = W + ((size_t)bb*Nn)*2304 + 768 + hh*64;    // k
    } else {
        Ab = A + (size_t)z*Nn*NPAD;
        Wb = W + (size_t)z*HDp*NPAD;
    }

    f32x4 acc[4][4];
#pragma unroll
    for (int i = 0; i < 4; ++i)
#pragma unroll
        for (int j = 0; j < 4; ++j) acc[i][j] = (f32x4){0.f,0.f,0.f,0.f};

    for (int k0 = 0; k0 < K; k0 += 32) {
        bf16x8 af[4], wf[4];
#pragma unroll
        for (int i = 0; i < 4; ++i) {
            int r = m0 + i*16 + rid; if (r > M-1) r = M-1;
            af[i] = *(const bf16x8*)(Ab + (size_t)r*lda + k0 + kq);
        }
#pragma unroll
        for (int j = 0; j < 4; ++j) {
            int c = n0 + j*16 + rid; if (c > N-1) c = N-1;
            wf[j] = *(const bf16x8*)(Wb + (size_t)c*ldw + k0 + kq);
        }
#pragma unroll
        for (int i = 0; i < 4; ++i)
#pragma unroll
            for (int j = 0; j < 4; ++j)
                acc[i][j] = __builtin_amdgcn_mfma_f32_16x16x32_bf16(af[i], wf[j], acc[i][j], 0, 0, 0);
    }

    const int rq = (lane >> 4) * 4;
    const int cc = lane & 15;

    if constexpr (EPI == 1) {
        float* cs = (float*)csm;
#pragma unroll
        for (int i = 0; i < 4; ++i)
#pragma unroll
            for (int j = 0; j < 4; ++j)
#pragma unroll
                for (int r = 0; r < 4; ++r)
                    cs[(m0 + i*16 + rq + r)*64 + j*16 + cc] = acc[i][j][r];
        __syncthreads();
        int hh = z - (z/12)*12;
        const float* bsrc = ef + (size_t)hh*NM;
        u16* P = (u16*)Cp + (size_t)z*Nn*NPAD;
        for (int sw = 0; sw < 13; ++sw) {
            int row = sw*16 + (tid >> 4);
            int col0 = (tid & 15) * 4;
            int gn = n0 + col0;
            if (row < Nn && gn < NPAD) {
                f32x4 v = *(const f32x4*)(cs + row*64 + col0);
                const float* bp = bsrc + (size_t)row*Nn + gn;
                float b0v = bp[0], b1v = bp[1], b2v = bp[2], b3v = bp[3];
                unsigned lo = (unsigned)f2b(v[0]+b0v) | ((unsigned)f2b(v[1]+b1v) << 16);
                unsigned hi = (unsigned)f2b(v[2]+b2v) | ((unsigned)f2b(v[3]+b3v) << 16);
                uint2 pk; pk.x = lo; pk.y = hi;
                *(uint2*)(P + (size_t)row*NPAD + gn) = pk;
            }
        }
    } else {
        u16* cs = csm;
#pragma unroll
        for (int i = 0; i < 4; ++i)
#pragma unroll
            for (int j = 0; j < 4; ++j)
#pragma unroll
                for (int r = 0; r < 4; ++r)
                    cs[(m0 + i*16 + rq + r)*64 + j*16 + cc] = f2b(acc[i][j][r]);
        __syncthreads();
        int bb = z/12, kk = z - bb*12;
        u16* Y = (u16*)Cp + ((size_t)(b0+bb)*Nn)*768 + kk*64;
        for (int sw = 0; sw < 7; ++sw) {
            int row = sw*32 + (tid >> 3);
            if (row < Nn) {
                int col0 = (tid & 7) * 8;
                *(uint4*)(Y + (size_t)row*768 + col0) = *(const uint4*)(cs + row*64 + col0);
            }
        }
    }
}

// ---------------- LayerNorm + affine + SSF: f32 in -> bf16 staging out ----------------
__global__ __launch_bounds__(256)
void ln_ssf(const float* __restrict__ x, const float* __restrict__ w, const float* __restrict__ bb,
            const float* __restrict__ sc, const float* __restrict__ sh, u16* __restrict__ out)
{
    const int row = blockIdx.x, tid = threadIdx.x;
    const float* xr = x + (size_t)row * 768;
    float v[3], s1 = 0.f, s2 = 0.f;
#pragma unroll
    for (int i = 0; i < 3; ++i) {
        float f = xr[tid + i*256];
        v[i] = f; s1 += f; s2 += f*f;
    }
    for (int o = 32; o > 0; o >>= 1) { s1 += __shfl_xor(s1, o); s2 += __shfl_xor(s2, o); }
    __shared__ float r1[4], r2[4];
    int wv = tid >> 6;
    if ((tid & 63) == 0) { r1[wv] = s1; r2[wv] = s2; }
    __syncthreads();
    s1 = r1[0]+r1[1]+r1[2]+r1[3];
    s2 = r2[0]+r2[1]+r2[2]+r2[3];
    float mean = s1 * (1.f/768.f);
    float var  = s2 * (1.f/768.f) - mean*mean;
    float rstd = rsqrtf(fmaxf(var, 0.f) + 1e-5f);
#pragma unroll
    for (int i = 0; i < 3; ++i) {
        int c = tid + i*256;
        float h = (v[i] - mean) * rstd * w[c] + bb[c];
        h = h * sc[c] + sh[c];
        out[(size_t)row*768 + c] = f2b(h);
    }
}

// ---------------- rel-pos bias gather ----------------
__global__ __launch_bounds__(256)
void bias_gather(const int* __restrict__ idx, const float* __restrict__ table, float* __restrict__ biasf)
{
    int t = blockIdx.x*256 + threadIdx.x;
    if (t >= NM) return;
    int id = idx[t];
#pragma unroll
    for (int h = 0; h < 12; ++h)
        biasf[(size_t)h*NM + t] = table[id*12 + h];
}

// ---------------- fused softmax + DCF head mixing (vectorized) ----------------
__global__ __launch_bounds__(256)
void softmax_dcf(u16* __restrict__ P, const float* __restrict__ bases, int nb)
{
    __shared__ float cf[144];
    int tid = threadIdx.x;
    if (tid < 144) {
        int k = tid / 12, h = tid - k*12;
        cf[h*12 + k] = bases[k*12 + h] + (h == k ? 1.f : 0.f);
    }
    __syncthreads();
    int ridx = blockIdx.x*4 + (tid >> 6);
    if (ridx >= nb*Nn) return;
    int lane = tid & 63;
    int m0 = lane * 4;
    int bb = ridx / Nn, n = ridx - bb*Nn;
    const size_t hs = (size_t)Nn*NPAD;
    u16* base = P + ((size_t)bb*12)*hs + (size_t)n*NPAD;

    float e[12][4];
#pragma unroll
    for (int h = 0; h < 12; ++h) {
        float s[4];
        if (m0 < NPAD) {
            uint2 pv = *(const uint2*)(base + h*hs + m0);
            s[0] = b2f((u16)(pv.x & 0xFFFF)); s[1] = b2f((u16)(pv.x >> 16));
            s[2] = b2f((u16)(pv.y & 0xFFFF)); s[3] = b2f((u16)(pv.y >> 16));
        } else { s[0]=s[1]=s[2]=s[3] = -1e30f; }
#pragma unroll
        for (int j = 0; j < 4; ++j) if (m0 + j >= Nn) s[j] = -1e30f;
        float mx = fmaxf(fmaxf(s[0], s[1]), fmaxf(s[2], s[3]));
        for (int o = 32; o > 0; o >>= 1) mx = fmaxf(mx, __shfl_xor(mx, o));
        float sum = 0.f;
#pragma unroll
        for (int j = 0; j < 4; ++j) {
            float ev = __expf(fmaxf(s[j] - mx, -80.f));
            if (m0 + j >= Nn) ev = 0.f;
            e[h][j] = ev; sum += ev;
        }
        for (int o = 32; o > 0; o >>= 1) sum += __shfl_xor(sum, o);
        float inv = 1.f / sum;
#pragma unroll
        for (int j = 0; j < 4; ++j) e[h][j] *= inv;
    }
    if (m0 < NPAD) {
#pragma unroll
        for (int k = 0; k < 12; ++k) {
            float o0 = 0.f, o1 = 0.f, o2 = 0.f, o3 = 0.f;
#pragma unroll
            for (int h = 0; h < 12; ++h) {
                float c = cf[h*12 + k];
                o0 += e[h][0]*c; o1 += e[h][1]*c; o2 += e[h][2]*c; o3 += e[h][3]*c;
            }
            unsigned lo = (unsigned)f2b(o0) | ((unsigned)f2b(o1) << 16);
            unsigned hi = (unsigned)f2b(o2) | ((unsigned)f2b(o3) << 16);
            uint2 pk; pk.x = lo; pk.y = hi;
            *(uint2*)(base + k*hs + m0) = pk;
        }
    }
}

// ---------------- v transpose per chunk-local (b,h) ----------------
__global__ __launch_bounds__(256)
void v_transpose(const u16* __restrict__ qkv, u16* __restrict__ vT)
{
    __shared__ u16 lds[64*198];
    int z = blockIdx.x;
    int bb = z/12, hh = z - bb*12;
    int tid = threadIdx.x;
    const u16* src = qkv + ((size_t)bb*Nn)*2304 + 1536 + hh*64;
    for (int e = tid; e < Nn*64; e += 256) {
        int m = e >> 6, d = e & 63;
        lds[d*198 + m] = src[(size_t)m*2304 + d];
    }
    __syncthreads();
    u16* dst = vT + (size_t)z*64*NPAD;
    for (int e = tid; e < 64*NPAD; e += 256) {
        int d = e / NPAD, m = e - d*NPAD;
        dst[e] = (m < Nn) ? lds[d*198 + m] : (u16)0;
    }
}

extern "C" void kernel_launch(void* const* d_in, const int* in_sizes, int n_in,
                              void* d_out, int out_size, void* d_ws, size_t ws_size,
                              hipStream_t stream)
{
    const float* x       = (const float*)d_in[0];
    const float* w_qkv   = (const float*)d_in[1];
    const float* q_bias  = (const float*)d_in[2];
    const float* v_bias  = (const float*)d_in[3];
    const float* s_qkv   = (const float*)d_in[4];
    const float* sh_qkv  = (const float*)d_in[5];
    const float* rel_tab = (const float*)d_in[6];
    const float* bases   = (const float*)d_in[7];
    const float* w_proj  = (const float*)d_in[8];
    const float* b_proj  = (const float*)d_in[9];
    const float* s_proj  = (const float*)d_in[10];
    const float* sh_proj = (const float*)d_in[11];
    const float* n1w     = (const float*)d_in[12];
    const float* n1b     = (const float*)d_in[13];
    const float* n2w     = (const float*)d_in[14];
    const float* n2b     = (const float*)d_in[15];
    const float* ss1     = (const float*)d_in[16];
    const float* ssh1    = (const float*)d_in[17];
    const float* ss2     = (const float*)d_in[18];
    const float* ssh2    = (const float*)d_in[19];
    const float* w_fc1   = (const float*)d_in[20];
    const float* b_fc1   = (const float*)d_in[21];
    const float* w_fc2   = (const float*)d_in[22];
    const float* b_fc2   = (const float*)d_in[23];
    const float* s_mlp   = (const float*)d_in[24];
    const float* sh_mlp  = (const float*)d_in[25];
    const float* g1      = (const float*)d_in[26];
    const float* g2      = (const float*)d_in[27];
    const int*   relidx  = (const int*)d_in[28];

    char*  ws   = (char*)d_ws;
    u16*   hbuf = (u16*)(ws + OFF_H);
    float* x1   = (float*)(ws + OFF_X1);
    float* bia  = (float*)(ws + OFF_BIA);
    u16*   wb   = (u16*)(ws + OFF_WB);
    float* out  = (float*)d_out;

    u16* wqkvB = wb + WQKV_E;
    u16* wprjB = wb + WPRJ_E;
    u16* wfc1B = wb + WFC1_E;
    u16* wfc2B = wb + WFC2_E;

    // 136KB dynamic LDS: 128KB main loop + padded epilogue C-tile (264-stride)
    hipFuncSetAttribute(reinterpret_cast<const void*>(&gemm256v<0>),
                        hipFuncAttributeMaxDynamicSharedMemorySize, 139264);
    hipFuncSetAttribute(reinterpret_cast<const void*>(&gemm256v<4>),
                        hipFuncAttributeMaxDynamicSharedMemorySize, 139264);
    hipFuncSetAttribute(reinterpret_cast<const void*>(&gemm256v<5>),
                        hipFuncAttributeMaxDynamicSharedMemorySize, 139264);
    hipFuncSetAttribute(reinterpret_cast<const void*>(&gemm128p<3>),
                        hipFuncAttributeMaxDynamicSharedMemorySize, 65536);

    int nb = 64;
    while (nb > 1 && OFF_CH + (size_t)nb*CHUNK_B > ws_size) nb >>= 1;
    const int nchunk = 64 / nb;
    u16* qkvC = (u16*)(ws + OFF_CH);
    u16* PC   = (u16*)(ws + OFF_CH + (size_t)nb*QKV_B);
    u16* vTC  = (u16*)(ws + OFF_CH + (size_t)nb*(QKV_B + P_B));

    // 0) weight conversion f32 -> bf16
    conv_b16<<<dim3(1728), dim3(256), 0, stream>>>(w_qkv, wqkvB, 442368);
    conv_b16<<<dim3(576),  dim3(256), 0, stream>>>(w_proj, wprjB, 147456);
    conv_b16<<<dim3(2304), dim3(256), 0, stream>>>(w_fc1, wfc1B, 589824);
    conv_b16<<<dim3(2304), dim3(256), 0, stream>>>(w_fc2, wfc2B, 589824);

    // 1) LN1 + SSF
    ln_ssf<<<dim3(ROWS), dim3(256), 0, stream>>>(x, n1w, n1b, ss1, ssh1, hbuf);
    // 2) rel-pos bias gather
    bias_gather<<<dim3(152), dim3(256), 0, stream>>>(relidx, rel_tab, bia);

    // 3) attention, chunked over batches
    for (int c = 0; c < nchunk; ++c) {
        const int b0 = c * nb;
        const int nrows = nb * Nn;
        const int gy = (nrows + 255) / 256;
        gemm256v<0><<<dim3(9, gy), dim3(512), 139264, stream>>>(
            hbuf + (size_t)b0*Nn*768, wqkvB, qkvC,
            nrows, 2304, 768, 768, 768, q_bias, v_bias, s_qkv, sh_qkv, nullptr);
        v_transpose<<<dim3(nb*12), dim3(256), 0, stream>>>(qkvC, vTC);
        gemm_nt<1><<<dim3(4, 1, nb*12), dim3(256), 0, stream>>>(
            qkvC, qkvC, PC, Nn, Nn, 64, 2304, 2304, 0, bia);
        softmax_dcf<<<dim3((nb*Nn + 3)/4), dim3(256), 0, stream>>>(PC, bases, nb);
        gemm_nt<2><<<dim3(1, 1, nb*12), dim3(256), 0, stream>>>(
            PC, vTC, hbuf, Nn, 64, NPAD, NPAD, NPAD, b0, nullptr);
    }

    // 4) proj + SSF + residual -> x1 (f32)  [128x128, 2 blocks/CU]
    gemm128p<3><<<dim3(6, 99), dim3(256), 65536, stream>>>(
        hbuf, wprjB, x1, ROWS, 768, 768, 768, 768,
        b_proj, s_proj, sh_proj, g1, x, nullptr);
    // 5) LN2 + SSF
    ln_ssf<<<dim3(ROWS), dim3(256), 0, stream>>>(x1, n2w, n2b, ss2, ssh2, hbuf);

    // 6) MLP, row-chunked into the (dead) attention chunk region
    u16* mlpC = qkvC;
    size_t avail = (ws_size > OFF_CH) ? (ws_size - OFF_CH) : (size_t)CHUNK_B;
    int nrM = (int)(avail / (MLPD * 2));
    if (nrM < 1) nrM = 1;
    if (nrM > ROWS) nrM = ROWS;
    for (int r0 = 0; r0 < ROWS; r0 += nrM) {
        int cr = ROWS - r0; if (cr > nrM) cr = nrM;
        int gy = (cr + 255) / 256;
        gemm256v<4><<<dim3(12, gy), dim3(512), 139264, stream>>>(
            hbuf + (size_t)r0*768, wfc1B, mlpC, cr, 3072, 768, 768, 768,
            b_fc1, nullptr, nullptr, nullptr, nullptr);
        gemm256v<5><<<dim3(3, gy), dim3(512), 139264, stream>>>(
            mlpC, wfc2B, out + (size_t)r0*768, cr, 768, 3072, 3072, 3072,
            b_fc2, s_mlp, sh_mlp, g2, x1 + (size_t)r0*768);
    }
}

// Round 7
// 715.921 us; speedup vs baseline: 1.0404x; 1.0404x over previous
//
#include <hip/hip_runtime.h>

typedef unsigned short u16;
using f32x4  = __attribute__((ext_vector_type(4))) float;
using bf16x8 = __attribute__((ext_vector_type(8))) __bf16;

#define Bz   64
#define Nn   197
#define Dd   768
#define Hh   12
#define HDp  64
#define MLPD 3072
#define ROWS (Bz*Nn)        /* 12608 */
#define NM   (Nn*Nn)        /* 38809 */
#define NPAD 224

// fixed region offsets (bytes)
#define OFF_H    0UL            /* hbuf bf16 12608x768 : 19,365,888 */
#define OFF_X1   19365888UL     /* x1   f32  12608x768 : 38,731,776 */
#define OFF_BIA  58097664UL     /* bias f32  12x197x197:  1,862,832 */
#define OFF_WB   59960496UL     /* bf16 weights        : 14,155,776 */
#define OFF_CH   74116272UL     /* chunked region */
// bf16 weight sub-offsets (elements)
#define WQKV_E 0UL
#define WPRJ_E 1769472UL
#define WFC1_E 2359296UL
#define WFC2_E 4718592UL
// per-batch chunk strides (bytes)
#define QKV_B  907776UL
#define P_B    1059072UL
#define VT_B   344064UL
#define CHUNK_B 2310912UL

__device__ inline float b2f(u16 v){ unsigned u = ((unsigned)v) << 16; float f; __builtin_memcpy(&f,&u,4); return f; }
__device__ inline u16 f2b(float f){ unsigned u; __builtin_memcpy(&u,&f,4); u += 0x7FFFu + ((u>>16)&1u); return (u16)(u>>16); }

// fast gelu: Abramowitz-Stegun 7.1.26 erf approx, |err(erf)| <= 1.5e-7
__device__ inline float gelu_f(float x){
    float z  = fabsf(x) * 0.70710678118f;
    float t  = 1.f / (1.f + 0.3275911f * z);
    float y  = t*(0.254829592f + t*(-0.284496736f + t*(1.421413741f + t*(-1.453152027f + t*1.061405429f))));
    float er = 1.f - y * __expf(-z*z);
    er = copysignf(er, x);
    return 0.5f * x * (1.f + er);
}

__device__ inline void gload_lds16(const u16* g, u16* l) {
    __builtin_amdgcn_global_load_lds((const __attribute__((address_space(1))) void*)g,
                                     (__attribute__((address_space(3))) void*)l, 16, 0, 0);
}

// ---------------- f32 -> bf16 convert (weights staging) ----------------
__global__ __launch_bounds__(256)
void conv_b16(const float* __restrict__ src, u16* __restrict__ dst, int n4)
{
    int t = blockIdx.x*256 + threadIdx.x;
    if (t >= n4) return;
    float4 v = *(const float4*)(src + (size_t)t*4);
    u16* d = dst + (size_t)t*4;
    d[0] = f2b(v.x); d[1] = f2b(v.y); d[2] = f2b(v.z); d[3] = f2b(v.w);
}

// ======== 256-row NT GEMM, R5-verified schedule, 64x64 wave tiles ========
// TH=1024/BN=256: 16 waves (4x4), acc=64 f32/thread -> ~128 regs -> 4 waves/SIMD.
// TH=512 /BN=128:  8 waves (4x2), 300-block grids for N=768.
// K-loop = R5's proven 4-phase counted-vmcnt schedule (staging interleaved per
// phase, wait vmcnt(ICA+ICB), never 0 in loop). Epilogue v2, padded C-tile.
// EPI: 0=qkv  4=fc1+gelu  5=fc2->out(f32, fused residual)
template<int EPI, int BN, int TH>
__global__ __launch_bounds__(TH)
void gemmv(const u16* __restrict__ A, const u16* __restrict__ W, void* __restrict__ Cp,
           int M, int N, int K, int lda, int ldw,
           const float* __restrict__ e0, const float* __restrict__ e1,
           const float* __restrict__ e2, const float* __restrict__ e3,
           const float* __restrict__ ef)
{
    extern __shared__ u16 lds[];
    constexpr int BM   = 256;
    constexpr int SWEEP = TH * 8;
    constexpr int ICA  = (BM * 32) / SWEEP;   // 1 (TH1024) or 2 (TH512)
    constexpr int ICB  = (BN * 32) / SWEEP;   // 1
    constexpr int VN   = ICA + ICB;           // 2 or 3
    constexpr int ASZ  = BM * 32;
    constexpr int BSZ  = BN * 32;
    constexpr int ABUF = 2 * ASZ;
    constexpr int BBUF = 2 * BSZ;
    constexpr int WCN  = BN / 64;             // 4 or 2
    constexpr int MF   = 4;                   // 64 rows per wave
    constexpr int MH   = 2;

    u16* sA = lds;
    u16* sB = lds + 2 * ABUF;

    const int tid  = threadIdx.x;
    const int lane = tid & 63;
    const int wave = tid >> 6;
    const int wr   = wave / WCN;              // 0..3
    const int wc   = wave % WCN;
    const int rid  = lane & 15;
    const int kg   = lane >> 4;
    const int m0   = blockIdx.y * BM;
    const int n0   = blockIdx.x * BN;
    const int t8   = tid * 8;

    const u16* asrc[2][ICA]; int adst[2][ICA];
    const u16* bsrc[2][ICB]; int bdst[2][ICB];
#pragma unroll
    for (int s = 0; s < 2; ++s) {
#pragma unroll
        for (int i = 0; i < ICA; ++i) {
            int e = i*SWEEP + t8, r = e >> 5;
            int g = ((e >> 3) & 3) ^ ((r >> 1) & 3);
            int row = m0 + r; if (row > M-1) row = M-1;
            asrc[s][i] = A + (size_t)row*lda + s*32 + g*8;
            adst[s][i] = s*ASZ + e;
        }
#pragma unroll
        for (int i = 0; i < ICB; ++i) {
            int e = i*SWEEP + t8, r = e >> 5;
            int g = ((e >> 3) & 3) ^ ((r >> 1) & 3);
            int col = n0 + r; if (col > N-1) col = N-1;
            bsrc[s][i] = W + (size_t)col*ldw + s*32 + g*8;
            bdst[s][i] = s*BSZ + e;
        }
    }

    const int koA   = (kg ^ ((rid >> 1) & 3)) * 8;
    const int aRow0 = (wr*64 + rid) * 32 + koA;
    const int bRow  = (wc*64 + rid) * 32 + koA;

    f32x4 acc[MF][4];
#pragma unroll
    for (int i = 0; i < MF; ++i)
#pragma unroll
        for (int j = 0; j < 4; ++j) acc[i][j] = (f32x4){0.f,0.f,0.f,0.f};

#define WAITBAR() do { \
        if constexpr (VN == 2)      asm volatile("s_waitcnt vmcnt(2) lgkmcnt(0)\n\ts_barrier" ::: "memory"); \
        else if constexpr (VN == 3) asm volatile("s_waitcnt vmcnt(3) lgkmcnt(0)\n\ts_barrier" ::: "memory"); \
        else                        asm volatile("s_waitcnt vmcnt(4) lgkmcnt(0)\n\ts_barrier" ::: "memory"); \
    } while (0)

    // ---- prologue: stage K-tile 0 into buf 0 (issue order pinned: s0 | s1) ----
#pragma unroll
    for (int i = 0; i < ICA; ++i) gload_lds16(asrc[0][i], sA + adst[0][i]);
#pragma unroll
    for (int i = 0; i < ICB; ++i) gload_lds16(bsrc[0][i], sB + bdst[0][i]);
    asm volatile("" ::: "memory");
#pragma unroll
    for (int i = 0; i < ICA; ++i) gload_lds16(asrc[1][i], sA + adst[1][i]);
#pragma unroll
    for (int i = 0; i < ICB; ++i) gload_lds16(bsrc[1][i], sB + bdst[1][i]);
    WAITBAR();

    const int NT = K >> 6;
    for (int t = 0; t < NT; ++t) {
        const int p  = t & 1;
        const size_t kpre = (size_t)(t + 1) * 64;
        const u16* paB = sA + p * ABUF;
        const u16* pbB = sB + p * BBUF;
        const int  qa  = (p ^ 1) * ABUF;
        const int  qb  = (p ^ 1) * BBUF;
        bf16x8 af[MH], wf[4];

        {   // phase 0: slice 0, m-half 0; stage A-s0(t+1)
            const u16* pa = paB + aRow0;
#pragma unroll
            for (int f = 0; f < MH; ++f) af[f] = *(const bf16x8*)(pa + f*512);
            const u16* pb = pbB + bRow;
#pragma unroll
            for (int j = 0; j < 4; ++j) wf[j] = *(const bf16x8*)(pb + j*512);
#pragma unroll
            for (int i = 0; i < ICA; ++i) gload_lds16(asrc[0][i] + kpre, sA + adst[0][i] + qa);
            __builtin_amdgcn_s_setprio(1);
#pragma unroll
            for (int f = 0; f < MH; ++f)
#pragma unroll
                for (int j = 0; j < 4; ++j)
                    acc[f][j] = __builtin_amdgcn_mfma_f32_16x16x32_bf16(af[f], wf[j], acc[f][j], 0, 0, 0);
            __builtin_amdgcn_s_setprio(0);
        }
        {   // phase 1: slice 0, m-half 1 (reuses wf); stage B-s0(t+1)
            const u16* pa = paB + aRow0 + MH*512;
#pragma unroll
            for (int f = 0; f < MH; ++f) af[f] = *(const bf16x8*)(pa + f*512);
#pragma unroll
            for (int i = 0; i < ICB; ++i) gload_lds16(bsrc[0][i] + kpre, sB + bdst[0][i] + qb);
            __builtin_amdgcn_s_setprio(1);
#pragma unroll
            for (int f = 0; f < MH; ++f)
#pragma unroll
                for (int j = 0; j < 4; ++j)
                    acc[MH+f][j] = __builtin_amdgcn_mfma_f32_16x16x32_bf16(af[f], wf[j], acc[MH+f][j], 0, 0, 0);
            __builtin_amdgcn_s_setprio(0);
        }
        WAITBAR();   // drains s1(t); s0(t+1) stays in flight
        {   // phase 2: slice 1, m-half 0; stage A-s1(t+1)
            const u16* pa = paB + ASZ + aRow0;
#pragma unroll
            for (int f = 0; f < MH; ++f) af[f] = *(const bf16x8*)(pa + f*512);
            const u16* pb = pbB + BSZ + bRow;
#pragma unroll
            for (int j = 0; j < 4; ++j) wf[j] = *(const bf16x8*)(pb + j*512);
#pragma unroll
            for (int i = 0; i < ICA; ++i) gload_lds16(asrc[1][i] + kpre, sA + adst[1][i] + qa);
            __builtin_amdgcn_s_setprio(1);
#pragma unroll
            for (int f = 0; f < MH; ++f)
#pragma unroll
                for (int j = 0; j < 4; ++j)
                    acc[f][j] = __builtin_amdgcn_mfma_f32_16x16x32_bf16(af[f], wf[j], acc[f][j], 0, 0, 0);
            __builtin_amdgcn_s_setprio(0);
        }
        {   // phase 3: slice 1, m-half 1; stage B-s1(t+1)
            const u16* pa = paB + ASZ + aRow0 + MH*512;
#pragma unroll
            for (int f = 0; f < MH; ++f) af[f] = *(const bf16x8*)(pa + f*512);
#pragma unroll
            for (int i = 0; i < ICB; ++i) gload_lds16(bsrc[1][i] + kpre, sB + bdst[1][i] + qb);
            __builtin_amdgcn_s_setprio(1);
#pragma unroll
            for (int f = 0; f < MH; ++f)
#pragma unroll
                for (int j = 0; j < 4; ++j)
                    acc[MH+f][j] = __builtin_amdgcn_mfma_f32_16x16x32_bf16(af[f], wf[j], acc[MH+f][j], 0, 0, 0);
            __builtin_amdgcn_s_setprio(0);
        }
        WAITBAR();   // drains s0(t+1) before next iter reads it
    }
    asm volatile("s_waitcnt vmcnt(0)" ::: "memory");
    __syncthreads();
#undef WAITBAR

    // ---- epilogue v2 ----
    float* ka = (float*)lds;
    float* kb = ka + BN;
    if (tid < BN) {
        int gn = n0 + tid;
        if constexpr (EPI == 0) {
            float mql = (gn < 768) ? 0.125f : 1.f;
            float bias = 0.f;
            if (gn < 768) bias = e0[gn];
            else if (gn >= 1536) bias = e1[gn-1536];
            float sc = e2[gn];
            ka[tid] = sc * mql;
            kb[tid] = (bias * sc + e3[gn]) * mql;
        } else if constexpr (EPI == 4) {
            ka[tid] = 0.f;
            kb[tid] = e0[gn];
        } else {
            float sc = e1[gn];
            ka[tid] = sc;
            kb[tid] = e0[gn]*sc + e2[gn];
        }
    }
    __syncthreads();
    const int rq = (lane >> 4) * 4;
    const int cc = lane & 15;
    float kaj[4], kbj[4];
#pragma unroll
    for (int j = 0; j < 4; ++j) {
        int c = wc*64 + j*16 + cc;
        kaj[j] = ka[c]; kbj[j] = kb[c];
    }
    __syncthreads();   // done reading coeffs; LDS reusable as C-tile

    if constexpr (EPI == 0 || EPI == 4) {
        // bf16 output: full 256 x (264-padded) u16 tile; vectorized 16B stores
        u16* ct = lds;
#pragma unroll
        for (int i = 0; i < MF; ++i) {
#pragma unroll
            for (int j = 0; j < 4; ++j) {
#pragma unroll
                for (int r = 0; r < 4; ++r) {
                    int rowL = wr*64 + i*16 + rq + r;
                    int col  = wc*64 + j*16 + cc;
                    float v = acc[i][j][r];
                    u16 o;
                    if constexpr (EPI == 0) o = f2b(v*kaj[j] + kbj[j]);
                    else                    o = f2b(gelu_f(v + kbj[j]));
                    ct[rowL*264 + col] = o;
                }
            }
        }
        __syncthreads();
        constexpr int ldc = (EPI == 0) ? 2304 : 3072;
        u16* C = (u16*)Cp;
        constexpr int RPS = TH / 32;          // rows per sweep (32 at TH=1024)
#pragma unroll
        for (int sw = 0; sw < 256/RPS; ++sw) {
            int rowL = sw*RPS + (tid >> 5);
            int gm = m0 + rowL;
            if (gm < M) {
                int col0 = (tid & 31) * 8;
                *(uint4*)(C + (size_t)gm*ldc + n0 + col0) =
                    *(const uint4*)(ct + rowL*264 + col0);
            }
        }
    } else {
        // f32 output + fused residual (BN=128, TH=512): two 128 x 132 f32 half-tiles
        float* cf = (float*)lds;
        float* C = (float*)Cp;
#pragma unroll
        for (int h = 0; h < 2; ++h) {
            if ((wr >> 1) == h) {
#pragma unroll
                for (int i = 0; i < MF; ++i) {
#pragma unroll
                    for (int j = 0; j < 4; ++j) {
#pragma unroll
                        for (int r = 0; r < 4; ++r) {
                            int rowH = (wr & 1)*64 + i*16 + rq + r;
                            int col  = wc*64 + j*16 + cc;
                            cf[rowH*132 + col] = acc[i][j][r]*kaj[j] + kbj[j];
                        }
                    }
                }
            }
            __syncthreads();
#pragma unroll
            for (int sw = 0; sw < 8; ++sw) {
                int rowH = sw*16 + (tid >> 5);
                int gm = m0 + h*128 + rowH;
                if (gm < M) {
                    int col0 = (tid & 31) * 4;
                    f32x4 v  = *(const f32x4*)(cf + rowH*132 + col0);
                    size_t gidx = (size_t)gm*768 + n0 + col0;
                    f32x4 xv = *(const f32x4*)(ef + gidx);
                    f32x4 g3 = *(const f32x4*)(e3 + n0 + col0);
                    f32x4 o;
#pragma unroll
                    for (int q = 0; q < 4; ++q) o[q] = xv[q] + g3[q]*v[q];
                    *(f32x4*)(C + gidx) = o;
                }
            }
            __syncthreads();
        }
    }
}

// ======== 128x128 pipelined NT GEMM, 2 blocks/CU (proj only; R5-verified) ========
// EPI: 3=proj->x1(f32, fused residual)
template<int EPI>
__global__ __launch_bounds__(256, 2)
void gemm128p(const u16* __restrict__ A, const u16* __restrict__ W, void* __restrict__ Cp,
              int M, int N, int K, int lda, int ldw,
              const float* __restrict__ e0, const float* __restrict__ e1,
              const float* __restrict__ e2, const float* __restrict__ e3,
              const float* __restrict__ e4, const float* __restrict__ ef)
{
    extern __shared__ u16 lds[];
    constexpr int SWEEP = 2048;
    constexpr int ICA  = 2;
    constexpr int ICB  = 2;
    constexpr int ASZ  = 128 * 32;
    constexpr int BSZ  = 128 * 32;
    constexpr int ABUF = 2 * ASZ;
    constexpr int BBUF = 2 * BSZ;
    constexpr int MF   = 4;
    constexpr int MH   = 2;

    u16* sA = lds;
    u16* sB = lds + 2 * ABUF;

    const int tid  = threadIdx.x;
    const int lane = tid & 63;
    const int wave = tid >> 6;
    const int wr   = wave >> 1;
    const int wc   = wave & 1;
    const int rid  = lane & 15;
    const int kg   = lane >> 4;
    const int m0   = blockIdx.y * 128;
    const int n0   = blockIdx.x * 128;
    const int t8   = tid * 8;

    const u16* asrc[2][ICA]; int adst[2][ICA];
    const u16* bsrc[2][ICB]; int bdst[2][ICB];
#pragma unroll
    for (int s = 0; s < 2; ++s) {
#pragma unroll
        for (int i = 0; i < ICA; ++i) {
            int e = i*SWEEP + t8, r = e >> 5;
            int g = ((e >> 3) & 3) ^ ((r >> 1) & 3);
            int row = m0 + r; if (row > M-1) row = M-1;
            asrc[s][i] = A + (size_t)row*lda + s*32 + g*8;
            adst[s][i] = s*ASZ + e;
        }
#pragma unroll
        for (int i = 0; i < ICB; ++i) {
            int e = i*SWEEP + t8, r = e >> 5;
            int g = ((e >> 3) & 3) ^ ((r >> 1) & 3);
            int col = n0 + r; if (col > N-1) col = N-1;
            bsrc[s][i] = W + (size_t)col*ldw + s*32 + g*8;
            bdst[s][i] = s*BSZ + e;
        }
    }

    const int koA   = (kg ^ ((rid >> 1) & 3)) * 8;
    const int aRow0 = (wr*64 + rid) * 32 + koA;
    const int bRow  = (wc*64 + rid) * 32 + koA;

    f32x4 acc[MF][4];
#pragma unroll
    for (int i = 0; i < MF; ++i)
#pragma unroll
        for (int j = 0; j < 4; ++j) acc[i][j] = (f32x4){0.f,0.f,0.f,0.f};

#define WAITBAR() asm volatile("s_waitcnt vmcnt(4) lgkmcnt(0)\n\ts_barrier" ::: "memory")

#pragma unroll
    for (int i = 0; i < ICA; ++i) gload_lds16(asrc[0][i], sA + adst[0][i]);
#pragma unroll
    for (int i = 0; i < ICB; ++i) gload_lds16(bsrc[0][i], sB + bdst[0][i]);
    asm volatile("" ::: "memory");
#pragma unroll
    for (int i = 0; i < ICA; ++i) gload_lds16(asrc[1][i], sA + adst[1][i]);
#pragma unroll
    for (int i = 0; i < ICB; ++i) gload_lds16(bsrc[1][i], sB + bdst[1][i]);
    WAITBAR();

    const int NT = K >> 6;
    for (int t = 0; t < NT; ++t) {
        const int p  = t & 1;
        const size_t kpre = (size_t)(t + 1) * 64;
        const u16* paB = sA + p * ABUF;
        const u16* pbB = sB + p * BBUF;
        const int  qa  = (p ^ 1) * ABUF;
        const int  qb  = (p ^ 1) * BBUF;
        bf16x8 af[MH], wf[4];

        {
            const u16* pa = paB + aRow0;
#pragma unroll
            for (int f = 0; f < MH; ++f) af[f] = *(const bf16x8*)(pa + f*512);
            const u16* pb = pbB + bRow;
#pragma unroll
            for (int j = 0; j < 4; ++j) wf[j] = *(const bf16x8*)(pb + j*512);
#pragma unroll
            for (int i = 0; i < ICA; ++i) gload_lds16(asrc[0][i] + kpre, sA + adst[0][i] + qa);
            __builtin_amdgcn_s_setprio(1);
#pragma unroll
            for (int f = 0; f < MH; ++f)
#pragma unroll
                for (int j = 0; j < 4; ++j)
                    acc[f][j] = __builtin_amdgcn_mfma_f32_16x16x32_bf16(af[f], wf[j], acc[f][j], 0, 0, 0);
            __builtin_amdgcn_s_setprio(0);
        }
        {
            const u16* pa = paB + aRow0 + MH*512;
#pragma unroll
            for (int f = 0; f < MH; ++f) af[f] = *(const bf16x8*)(pa + f*512);
#pragma unroll
            for (int i = 0; i < ICB; ++i) gload_lds16(bsrc[0][i] + kpre, sB + bdst[0][i] + qb);
            __builtin_amdgcn_s_setprio(1);
#pragma unroll
            for (int f = 0; f < MH; ++f)
#pragma unroll
                for (int j = 0; j < 4; ++j)
                    acc[MH+f][j] = __builtin_amdgcn_mfma_f32_16x16x32_bf16(af[f], wf[j], acc[MH+f][j], 0, 0, 0);
            __builtin_amdgcn_s_setprio(0);
        }
        WAITBAR();
        {
            const u16* pa = paB + ASZ + aRow0;
#pragma unroll
            for (int f = 0; f < MH; ++f) af[f] = *(const bf16x8*)(pa + f*512);
            const u16* pb = pbB + BSZ + bRow;
#pragma unroll
            for (int j = 0; j < 4; ++j) wf[j] = *(const bf16x8*)(pb + j*512);
#pragma unroll
            for (int i = 0; i < ICA; ++i) gload_lds16(asrc[1][i] + kpre, sA + adst[1][i] + qa);
            __builtin_amdgcn_s_setprio(1);
#pragma unroll
            for (int f = 0; f < MH; ++f)
#pragma unroll
                for (int j = 0; j < 4; ++j)
                    acc[f][j] = __builtin_amdgcn_mfma_f32_16x16x32_bf16(af[f], wf[j], acc[f][j], 0, 0, 0);
            __builtin_amdgcn_s_setprio(0);
        }
        {
            const u16* pa = paB + ASZ + aRow0 + MH*512;
#pragma unroll
            for (int f = 0; f < MH; ++f) af[f] = *(const bf16x8*)(pa + f*512);
#pragma unroll
            for (int i = 0; i < ICB; ++i) gload_lds16(bsrc[1][i] + kpre, sB + bdst[1][i] + qb);
            __builtin_amdgcn_s_setprio(1);
#pragma unroll
            for (int f = 0; f < MH; ++f)
#pragma unroll
                for (int j = 0; j < 4; ++j)
                    acc[MH+f][j] = __builtin_amdgcn_mfma_f32_16x16x32_bf16(af[f], wf[j], acc[MH+f][j], 0, 0, 0);
            __builtin_amdgcn_s_setprio(0);
        }
        WAITBAR();
    }
    asm volatile("s_waitcnt vmcnt(0)" ::: "memory");
    __syncthreads();
#undef WAITBAR

    float* ka = (float*)lds;
    float* kb = ka + 128;
    if (tid < 128) {
        int gn = n0 + tid;
        float sc = e1[gn];
        ka[tid] = sc;
        kb[tid] = e0[gn]*sc + e2[gn];
    }
    __syncthreads();
    const int rq = (lane >> 4) * 4;
    const int cc = lane & 15;
    float kaj[4], kbj[4];
#pragma unroll
    for (int j = 0; j < 4; ++j) {
        int c = wc*64 + j*16 + cc;
        kaj[j] = ka[c]; kbj[j] = kb[c];
    }
    __syncthreads();

    float* cf = (float*)lds;
    const float* RES = e4;
    float* C = (float*)Cp;
#pragma unroll
    for (int h = 0; h < 2; ++h) {
        if (wr == h) {
#pragma unroll
            for (int i = 0; i < MF; ++i) {
#pragma unroll
                for (int j = 0; j < 4; ++j) {
#pragma unroll
                    for (int r = 0; r < 4; ++r) {
                        int rowH = i*16 + rq + r;
                        int col  = wc*64 + j*16 + cc;
                        cf[rowH*132 + col] = acc[i][j][r]*kaj[j] + kbj[j];
                    }
                }
            }
        }
        __syncthreads();
#pragma unroll
        for (int sw = 0; sw < 8; ++sw) {
            int rowH = sw*8 + (tid >> 5);
            int gm = m0 + h*64 + rowH;
            if (gm < M) {
                int col0 = (tid & 31) * 4;
                f32x4 v  = *(const f32x4*)(cf + rowH*132 + col0);
                size_t gidx = (size_t)gm*768 + n0 + col0;
                f32x4 xv = *(const f32x4*)(RES + gidx);
                f32x4 g3 = *(const f32x4*)(e3 + n0 + col0);
                f32x4 o;
#pragma unroll
                for (int q = 0; q < 4; ++q) o[q] = xv[q] + g3[q]*v[q];
                *(f32x4*)(C + gidx) = o;
            }
        }
        __syncthreads();
    }
}

// ======== direct-load NT GEMM for small-K attention GEMMs ========
template<int EPI>
__global__ __launch_bounds__(256)
void gemm_nt(const u16* __restrict__ A, const u16* __restrict__ W, void* __restrict__ Cp,
             int M, int N, int K, int lda, int ldw, int b0,
             const float* __restrict__ ef)
{
    __shared__ __align__(16) u16 csm[(EPI == 1) ? 32768 : 16384];
    const int tid  = threadIdx.x;
    const int lane = tid & 63;
    const int wave = tid >> 6;
    const int z    = blockIdx.z;
    const int m0   = wave*64;
    const int n0   = blockIdx.x*64;
    const int rid  = lane & 15;
    const int kq   = (lane >> 4) * 8;

    const u16* Ab = A;
    const u16* Wb = W;
    if constexpr (EPI == 1) {
        int bb = z/12, hh = z - bb*12;
        Ab = A + ((size_t)bb*Nn)*2304 + hh*64;
        Wb = W + ((size_t)bb*Nn)*2304 + 768 + hh*64;
    } else {
        Ab = A + (size_t)z*Nn*NPAD;
        Wb = W + (size_t)z*HDp*NPAD;
    }

    f32x4 acc[4][4];
#pragma unroll
    for (int i = 0; i < 4; ++i)
#pragma unroll
        for (int j = 0; j < 4; ++j) acc[i][j] = (f32x4){0.f,0.f,0.f,0.f};

    for (int k0 = 0; k0 < K; k0 += 32) {
        bf16x8 af[4], wf[4];
#pragma unroll
        for (int i = 0; i < 4; ++i) {
            int r = m0 + i*16 + rid; if (r > M-1) r = M-1;
            af[i] = *(const bf16x8*)(Ab + (size_t)r*lda + k0 + kq);
        }
#pragma unroll
        for (int j = 0; j < 4; ++j) {
            int c = n0 + j*16 + rid; if (c > N-1) c = N-1;
            wf[j] = *(const bf16x8*)(Wb + (size_t)c*ldw + k0 + kq);
        }
#pragma unroll
        for (int i = 0; i < 4; ++i)
#pragma unroll
            for (int j = 0; j < 4; ++j)
                acc[i][j] = __builtin_amdgcn_mfma_f32_16x16x32_bf16(af[i], wf[j], acc[i][j], 0, 0, 0);
    }

    const int rq = (lane >> 4) * 4;
    const int cc = lane & 15;

    if constexpr (EPI == 1) {
        float* cs = (float*)csm;
#pragma unroll
        for (int i = 0; i < 4; ++i)
#pragma unroll
            for (int j = 0; j < 4; ++j)
#pragma unroll
                for (int r = 0; r < 4; ++r)
                    cs[(m0 + i*16 + rq + r)*64 + j*16 + cc] = acc[i][j][r];
        __syncthreads();
        int hh = z - (z/12)*12;
        const float* bsrc = ef + (size_t)hh*NM;
        u16* P = (u16*)Cp + (size_t)z*Nn*NPAD;
        for (int sw = 0; sw < 13; ++sw) {
            int row = sw*16 + (tid >> 4);
            int col0 = (tid & 15) * 4;
            int gn = n0 + col0;
            if (row < Nn && gn < NPAD) {
                f32x4 v = *(const f32x4*)(cs + row*64 + col0);
                const float* bp = bsrc + (size_t)row*Nn + gn;
                float b0v = bp[0], b1v = bp[1], b2v = bp[2], b3v = bp[3];
                unsigned lo = (unsigned)f2b(v[0]+b0v) | ((unsigned)f2b(v[1]+b1v) << 16);
                unsigned hi = (unsigned)f2b(v[2]+b2v) | ((unsigned)f2b(v[3]+b3v) << 16);
                uint2 pk; pk.x = lo; pk.y = hi;
                *(uint2*)(P + (size_t)row*NPAD + gn) = pk;
            }
        }
    } else {
        u16* cs = csm;
#pragma unroll
        for (int i = 0; i < 4; ++i)
#pragma unroll
            for (int j = 0; j < 4; ++j)
#pragma unroll
                for (int r = 0; r < 4; ++r)
                    cs[(m0 + i*16 + rq + r)*64 + j*16 + cc] = f2b(acc[i][j][r]);
        __syncthreads();
        int bb = z/12, kk = z - bb*12;
        u16* Y = (u16*)Cp + ((size_t)(b0+bb)*Nn)*768 + kk*64;
        for (int sw = 0; sw < 7; ++sw) {
            int row = sw*32 + (tid >> 3);
            if (row < Nn) {
                int col0 = (tid & 7) * 8;
                *(uint4*)(Y + (size_t)row*768 + col0) = *(const uint4*)(cs + row*64 + col0);
            }
        }
    }
}

// ---------------- LayerNorm + affine + SSF: f32 in -> bf16 staging out ----------------
__global__ __launch_bounds__(256)
void ln_ssf(const float* __restrict__ x, const float* __restrict__ w, const float* __restrict__ bb,
            const float* __restrict__ sc, const float* __restrict__ sh, u16* __restrict__ out)
{
    const int row = blockIdx.x, tid = threadIdx.x;
    const float* xr = x + (size_t)row * 768;
    float v[3], s1 = 0.f, s2 = 0.f;
#pragma unroll
    for (int i = 0; i < 3; ++i) {
        float f = xr[tid + i*256];
        v[i] = f; s1 += f; s2 += f*f;
    }
    for (int o = 32; o > 0; o >>= 1) { s1 += __shfl_xor(s1, o); s2 += __shfl_xor(s2, o); }
    __shared__ float r1[4], r2[4];
    int wv = tid >> 6;
    if ((tid & 63) == 0) { r1[wv] = s1; r2[wv] = s2; }
    __syncthreads();
    s1 = r1[0]+r1[1]+r1[2]+r1[3];
    s2 = r2[0]+r2[1]+r2[2]+r2[3];
    float mean = s1 * (1.f/768.f);
    float var  = s2 * (1.f/768.f) - mean*mean;
    float rstd = rsqrtf(fmaxf(var, 0.f) + 1e-5f);
#pragma unroll
    for (int i = 0; i < 3; ++i) {
        int c = tid + i*256;
        float h = (v[i] - mean) * rstd * w[c] + bb[c];
        h = h * sc[c] + sh[c];
        out[(size_t)row*768 + c] = f2b(h);
    }
}

// ---------------- rel-pos bias gather ----------------
__global__ __launch_bounds__(256)
void bias_gather(const int* __restrict__ idx, const float* __restrict__ table, float* __restrict__ biasf)
{
    int t = blockIdx.x*256 + threadIdx.x;
    if (t >= NM) return;
    int id = idx[t];
#pragma unroll
    for (int h = 0; h < 12; ++h)
        biasf[(size_t)h*NM + t] = table[id*12 + h];
}

// ---------------- fused softmax + DCF head mixing (vectorized) ----------------
__global__ __launch_bounds__(256)
void softmax_dcf(u16* __restrict__ P, const float* __restrict__ bases, int nb)
{
    __shared__ float cf[144];
    int tid = threadIdx.x;
    if (tid < 144) {
        int k = tid / 12, h = tid - k*12;
        cf[h*12 + k] = bases[k*12 + h] + (h == k ? 1.f : 0.f);
    }
    __syncthreads();
    int ridx = blockIdx.x*4 + (tid >> 6);
    if (ridx >= nb*Nn) return;
    int lane = tid & 63;
    int m0 = lane * 4;
    int bb = ridx / Nn, n = ridx - bb*Nn;
    const size_t hs = (size_t)Nn*NPAD;
    u16* base = P + ((size_t)bb*12)*hs + (size_t)n*NPAD;

    float e[12][4];
#pragma unroll
    for (int h = 0; h < 12; ++h) {
        float s[4];
        if (m0 < NPAD) {
            uint2 pv = *(const uint2*)(base + h*hs + m0);
            s[0] = b2f((u16)(pv.x & 0xFFFF)); s[1] = b2f((u16)(pv.x >> 16));
            s[2] = b2f((u16)(pv.y & 0xFFFF)); s[3] = b2f((u16)(pv.y >> 16));
        } else { s[0]=s[1]=s[2]=s[3] = -1e30f; }
#pragma unroll
        for (int j = 0; j < 4; ++j) if (m0 + j >= Nn) s[j] = -1e30f;
        float mx = fmaxf(fmaxf(s[0], s[1]), fmaxf(s[2], s[3]));
        for (int o = 32; o > 0; o >>= 1) mx = fmaxf(mx, __shfl_xor(mx, o));
        float sum = 0.f;
#pragma unroll
        for (int j = 0; j < 4; ++j) {
            float ev = __expf(fmaxf(s[j] - mx, -80.f));
            if (m0 + j >= Nn) ev = 0.f;
            e[h][j] = ev; sum += ev;
        }
        for (int o = 32; o > 0; o >>= 1) sum += __shfl_xor(sum, o);
        float inv = 1.f / sum;
#pragma unroll
        for (int j = 0; j < 4; ++j) e[h][j] *= inv;
    }
    if (m0 < NPAD) {
#pragma unroll
        for (int k = 0; k < 12; ++k) {
            float o0 = 0.f, o1 = 0.f, o2 = 0.f, o3 = 0.f;
#pragma unroll
            for (int h = 0; h < 12; ++h) {
                float c = cf[h*12 + k];
                o0 += e[h][0]*c; o1 += e[h][1]*c; o2 += e[h][2]*c; o3 += e[h][3]*c;
            }
            unsigned lo = (unsigned)f2b(o0) | ((unsigned)f2b(o1) << 16);
            unsigned hi = (unsigned)f2b(o2) | ((unsigned)f2b(o3) << 16);
            uint2 pk; pk.x = lo; pk.y = hi;
            *(uint2*)(base + k*hs + m0) = pk;
        }
    }
}

// ---------------- v transpose per chunk-local (b,h) ----------------
__global__ __launch_bounds__(256)
void v_transpose(const u16* __restrict__ qkv, u16* __restrict__ vT)
{
    __shared__ u16 lds[64*198];
    int z = blockIdx.x;
    int bb = z/12, hh = z - bb*12;
    int tid = threadIdx.x;
    const u16* src = qkv + ((size_t)bb*Nn)*2304 + 1536 + hh*64;
    for (int e = tid; e < Nn*64; e += 256) {
        int m = e >> 6, d = e & 63;
        lds[d*198 + m] = src[(size_t)m*2304 + d];
    }
    __syncthreads();
    u16* dst = vT + (size_t)z*64*NPAD;
    for (int e = tid; e < 64*NPAD; e += 256) {
        int d = e / NPAD, m = e - d*NPAD;
        dst[e] = (m < Nn) ? lds[d*198 + m] : (u16)0;
    }
}

extern "C" void kernel_launch(void* const* d_in, const int* in_sizes, int n_in,
                              void* d_out, int out_size, void* d_ws, size_t ws_size,
                              hipStream_t stream)
{
    const float* x       = (const float*)d_in[0];
    const float* w_qkv   = (const float*)d_in[1];
    const float* q_bias  = (const float*)d_in[2];
    const float* v_bias  = (const float*)d_in[3];
    const float* s_qkv   = (const float*)d_in[4];
    const float* sh_qkv  = (const float*)d_in[5];
    const float* rel_tab = (const float*)d_in[6];
    const float* bases   = (const float*)d_in[7];
    const float* w_proj  = (const float*)d_in[8];
    const float* b_proj  = (const float*)d_in[9];
    const float* s_proj  = (const float*)d_in[10];
    const float* sh_proj = (const float*)d_in[11];
    const float* n1w     = (const float*)d_in[12];
    const float* n1b     = (const float*)d_in[13];
    const float* n2w     = (const float*)d_in[14];
    const float* n2b     = (const float*)d_in[15];
    const float* ss1     = (const float*)d_in[16];
    const float* ssh1    = (const float*)d_in[17];
    const float* ss2     = (const float*)d_in[18];
    const float* ssh2    = (const float*)d_in[19];
    const float* w_fc1   = (const float*)d_in[20];
    const float* b_fc1   = (const float*)d_in[21];
    const float* w_fc2   = (const float*)d_in[22];
    const float* b_fc2   = (const float*)d_in[23];
    const float* s_mlp   = (const float*)d_in[24];
    const float* sh_mlp  = (const float*)d_in[25];
    const float* g1      = (const float*)d_in[26];
    const float* g2      = (const float*)d_in[27];
    const int*   relidx  = (const int*)d_in[28];

    char*  ws   = (char*)d_ws;
    u16*   hbuf = (u16*)(ws + OFF_H);
    float* x1   = (float*)(ws + OFF_X1);
    float* bia  = (float*)(ws + OFF_BIA);
    u16*   wb   = (u16*)(ws + OFF_WB);
    float* out  = (float*)d_out;

    u16* wqkvB = wb + WQKV_E;
    u16* wprjB = wb + WPRJ_E;
    u16* wfc1B = wb + WFC1_E;
    u16* wfc2B = wb + WFC2_E;

    hipFuncSetAttribute(reinterpret_cast<const void*>(&gemmv<0,256,1024>),
                        hipFuncAttributeMaxDynamicSharedMemorySize, 139264);
    hipFuncSetAttribute(reinterpret_cast<const void*>(&gemmv<4,256,1024>),
                        hipFuncAttributeMaxDynamicSharedMemorySize, 139264);
    hipFuncSetAttribute(reinterpret_cast<const void*>(&gemmv<5,128,512>),
                        hipFuncAttributeMaxDynamicSharedMemorySize, 98304);
    hipFuncSetAttribute(reinterpret_cast<const void*>(&gemm128p<3>),
                        hipFuncAttributeMaxDynamicSharedMemorySize, 65536);

    int nb = 64;
    while (nb > 1 && OFF_CH + (size_t)nb*CHUNK_B > ws_size) nb >>= 1;
    const int nchunk = 64 / nb;
    u16* qkvC = (u16*)(ws + OFF_CH);
    u16* PC   = (u16*)(ws + OFF_CH + (size_t)nb*QKV_B);
    u16* vTC  = (u16*)(ws + OFF_CH + (size_t)nb*(QKV_B + P_B));

    // 0) weight conversion f32 -> bf16
    conv_b16<<<dim3(1728), dim3(256), 0, stream>>>(w_qkv, wqkvB, 442368);
    conv_b16<<<dim3(576),  dim3(256), 0, stream>>>(w_proj, wprjB, 147456);
    conv_b16<<<dim3(2304), dim3(256), 0, stream>>>(w_fc1, wfc1B, 589824);
    conv_b16<<<dim3(2304), dim3(256), 0, stream>>>(w_fc2, wfc2B, 589824);

    // 1) LN1 + SSF
    ln_ssf<<<dim3(ROWS), dim3(256), 0, stream>>>(x, n1w, n1b, ss1, ssh1, hbuf);
    // 2) rel-pos bias gather
    bias_gather<<<dim3(152), dim3(256), 0, stream>>>(relidx, rel_tab, bia);

    // 3) attention, chunked over batches
    for (int c = 0; c < nchunk; ++c) {
        const int b0 = c * nb;
        const int nrows = nb * Nn;
        const int gy = (nrows + 255) / 256;
        gemmv<0,256,1024><<<dim3(9, gy), dim3(1024), 139264, stream>>>(
            hbuf + (size_t)b0*Nn*768, wqkvB, qkvC,
            nrows, 2304, 768, 768, 768, q_bias, v_bias, s_qkv, sh_qkv, nullptr);
        v_transpose<<<dim3(nb*12), dim3(256), 0, stream>>>(qkvC, vTC);
        gemm_nt<1><<<dim3(4, 1, nb*12), dim3(256), 0, stream>>>(
            qkvC, qkvC, PC, Nn, Nn, 64, 2304, 2304, 0, bia);
        softmax_dcf<<<dim3((nb*Nn + 3)/4), dim3(256), 0, stream>>>(PC, bases, nb);
        gemm_nt<2><<<dim3(1, 1, nb*12), dim3(256), 0, stream>>>(
            PC, vTC, hbuf, Nn, 64, NPAD, NPAD, NPAD, b0, nullptr);
    }

    // 4) proj + SSF + residual -> x1 (f32)  [128x128, 2 blocks/CU]
    gemm128p<3><<<dim3(6, 99), dim3(256), 65536, stream>>>(
        hbuf, wprjB, x1, ROWS, 768, 768, 768, 768,
        b_proj, s_proj, sh_proj, g1, x, nullptr);
    // 5) LN2 + SSF
    ln_ssf<<<dim3(ROWS), dim3(256), 0, stream>>>(x1, n2w, n2b, ss2, ssh2, hbuf);

    // 6) MLP, row-chunked into the (dead) attention chunk region
    u16* mlpC = qkvC;
    size_t avail = (ws_size > OFF_CH) ? (ws_size - OFF_CH) : (size_t)CHUNK_B;
    int nrM = (int)(avail / (MLPD * 2));
    if (nrM < 1) nrM = 1;
    if (nrM > ROWS) nrM = ROWS;
    for (int r0 = 0; r0 < ROWS; r0 += nrM) {
        int cr = ROWS - r0; if (cr > nrM) cr = nrM;
        int gy = (cr + 255) / 256;
        gemmv<4,256,1024><<<dim3(12, gy), dim3(1024), 139264, stream>>>(
            hbuf + (size_t)r0*768, wfc1B, mlpC, cr, 3072, 768, 768, 768,
            b_fc1, nullptr, nullptr, nullptr, nullptr);
        gemmv<5,128,512><<<dim3(6, gy), dim3(512), 98304, stream>>>(
            mlpC, wfc2B, out + (size_t)r0*768, cr, 768, 3072, 3072, 3072,
            b_fc2, s_mlp, sh_mlp, g2, x1 + (size_t)r0*768);
    }
}

// Round 8
// 659.487 us; speedup vs baseline: 1.1294x; 1.0856x over previous
//
#include <hip/hip_runtime.h>

typedef unsigned short u16;
using f32x4  = __attribute__((ext_vector_type(4))) float;
using bf16x8 = __attribute__((ext_vector_type(8))) __bf16;

#define Bz   64
#define Nn   197
#define Dd   768
#define Hh   12
#define HDp  64
#define MLPD 3072
#define ROWS (Bz*Nn)        /* 12608 */
#define NM   (Nn*Nn)        /* 38809 */
#define NPAD 224

// fixed region offsets (bytes)
#define OFF_H    0UL            /* hbuf bf16 12608x768 : 19,365,888 */
#define OFF_X1   19365888UL     /* x1   f32  12608x768 : 38,731,776 */
#define OFF_BIA  58097664UL     /* bias f32  12x197x197:  1,862,832 */
#define OFF_WB   59960496UL     /* bf16 weights        : 14,155,776 */
#define OFF_CH   74116272UL     /* chunked region */
// bf16 weight sub-offsets (elements)
#define WQKV_E 0UL
#define WPRJ_E 1769472UL
#define WFC1_E 2359296UL
#define WFC2_E 4718592UL
// per-batch chunk strides (bytes)
#define QKV_B  907776UL
#define P_B    1059072UL
#define VT_B   344064UL
#define CHUNK_B 2310912UL

__device__ inline float b2f(u16 v){ unsigned u = ((unsigned)v) << 16; float f; __builtin_memcpy(&f,&u,4); return f; }
__device__ inline u16 f2b(float f){ unsigned u; __builtin_memcpy(&u,&f,4); u += 0x7FFFu + ((u>>16)&1u); return (u16)(u>>16); }

// fast gelu: Abramowitz-Stegun 7.1.26 erf approx, |err(erf)| <= 1.5e-7
__device__ inline float gelu_f(float x){
    float z  = fabsf(x) * 0.70710678118f;
    float t  = 1.f / (1.f + 0.3275911f * z);
    float y  = t*(0.254829592f + t*(-0.284496736f + t*(1.421413741f + t*(-1.453152027f + t*1.061405429f))));
    float er = 1.f - y * __expf(-z*z);
    er = copysignf(er, x);
    return 0.5f * x * (1.f + er);
}

__device__ inline void gload_lds16(const u16* g, u16* l) {
    __builtin_amdgcn_global_load_lds((const __attribute__((address_space(1))) void*)g,
                                     (__attribute__((address_space(3))) void*)l, 16, 0, 0);
}

// ---------------- f32 -> bf16 convert (weights staging) ----------------
__global__ __launch_bounds__(256)
void conv_b16(const float* __restrict__ src, u16* __restrict__ dst, int n4)
{
    int t = blockIdx.x*256 + threadIdx.x;
    if (t >= n4) return;
    float4 v = *(const float4*)(src + (size_t)t*4);
    u16* d = dst + (size_t)t*4;
    d[0] = f2b(v.x); d[1] = f2b(v.y); d[2] = f2b(v.z); d[3] = f2b(v.w);
}

// ======== 256x256 NT GEMM, 16 waves of 64x64, R5-schedule (frozen) ========
// TH=1024: ICA=ICB=1, VN=2; acc=64 f32/thread -> ~128 regs -> 4 waves/SIMD.
// K-loop = proven 4-phase counted-vmcnt schedule (staging interleaved per phase,
// wait vmcnt(VN), never 0 in loop). Epilogue v2, padded C-tile.
// EPI: 0=qkv  4=fc1+gelu  5=fc2->out(f32, fused residual)
template<int EPI, int BN, int TH>
__global__ __launch_bounds__(TH)
void gemmv(const u16* __restrict__ A, const u16* __restrict__ W, void* __restrict__ Cp,
           int M, int N, int K, int lda, int ldw,
           const float* __restrict__ e0, const float* __restrict__ e1,
           const float* __restrict__ e2, const float* __restrict__ e3,
           const float* __restrict__ ef)
{
    extern __shared__ u16 lds[];
    constexpr int BM   = 256;
    constexpr int SWEEP = TH * 8;
    constexpr int ICA  = (BM * 32) / SWEEP;   // 1 at TH=1024
    constexpr int ICB  = (BN * 32) / SWEEP;   // 1
    constexpr int VN   = ICA + ICB;           // 2
    constexpr int ASZ  = BM * 32;
    constexpr int BSZ  = BN * 32;
    constexpr int ABUF = 2 * ASZ;
    constexpr int BBUF = 2 * BSZ;
    constexpr int WCN  = BN / 64;             // 4
    constexpr int MF   = 4;                   // 64 rows per wave
    constexpr int MH   = 2;

    u16* sA = lds;
    u16* sB = lds + 2 * ABUF;

    const int tid  = threadIdx.x;
    const int lane = tid & 63;
    const int wave = tid >> 6;
    const int wr   = wave / WCN;              // 0..3
    const int wc   = wave % WCN;
    const int rid  = lane & 15;
    const int kg   = lane >> 4;
    const int m0   = blockIdx.y * BM;
    const int n0   = blockIdx.x * BN;
    const int t8   = tid * 8;

    const u16* asrc[2][ICA]; int adst[2][ICA];
    const u16* bsrc[2][ICB]; int bdst[2][ICB];
#pragma unroll
    for (int s = 0; s < 2; ++s) {
#pragma unroll
        for (int i = 0; i < ICA; ++i) {
            int e = i*SWEEP + t8, r = e >> 5;
            int g = ((e >> 3) & 3) ^ ((r >> 1) & 3);
            int row = m0 + r; if (row > M-1) row = M-1;
            asrc[s][i] = A + (size_t)row*lda + s*32 + g*8;
            adst[s][i] = s*ASZ + e;
        }
#pragma unroll
        for (int i = 0; i < ICB; ++i) {
            int e = i*SWEEP + t8, r = e >> 5;
            int g = ((e >> 3) & 3) ^ ((r >> 1) & 3);
            int col = n0 + r; if (col > N-1) col = N-1;
            bsrc[s][i] = W + (size_t)col*ldw + s*32 + g*8;
            bdst[s][i] = s*BSZ + e;
        }
    }

    const int koA   = (kg ^ ((rid >> 1) & 3)) * 8;
    const int aRow0 = (wr*64 + rid) * 32 + koA;
    const int bRow  = (wc*64 + rid) * 32 + koA;

    f32x4 acc[MF][4];
#pragma unroll
    for (int i = 0; i < MF; ++i)
#pragma unroll
        for (int j = 0; j < 4; ++j) acc[i][j] = (f32x4){0.f,0.f,0.f,0.f};

#define WAITBAR() do { \
        if constexpr (VN == 2)      asm volatile("s_waitcnt vmcnt(2) lgkmcnt(0)\n\ts_barrier" ::: "memory"); \
        else if constexpr (VN == 3) asm volatile("s_waitcnt vmcnt(3) lgkmcnt(0)\n\ts_barrier" ::: "memory"); \
        else                        asm volatile("s_waitcnt vmcnt(4) lgkmcnt(0)\n\ts_barrier" ::: "memory"); \
    } while (0)

    // ---- prologue: stage K-tile 0 into buf 0 (issue order pinned: s0 | s1) ----
#pragma unroll
    for (int i = 0; i < ICA; ++i) gload_lds16(asrc[0][i], sA + adst[0][i]);
#pragma unroll
    for (int i = 0; i < ICB; ++i) gload_lds16(bsrc[0][i], sB + bdst[0][i]);
    asm volatile("" ::: "memory");
#pragma unroll
    for (int i = 0; i < ICA; ++i) gload_lds16(asrc[1][i], sA + adst[1][i]);
#pragma unroll
    for (int i = 0; i < ICB; ++i) gload_lds16(bsrc[1][i], sB + bdst[1][i]);
    WAITBAR();

    const int NT = K >> 6;
    for (int t = 0; t < NT; ++t) {
        const int p  = t & 1;
        const size_t kpre = (size_t)(t + 1) * 64;
        const u16* paB = sA + p * ABUF;
        const u16* pbB = sB + p * BBUF;
        const int  qa  = (p ^ 1) * ABUF;
        const int  qb  = (p ^ 1) * BBUF;
        bf16x8 af[MH], wf[4];

        {   // phase 0: slice 0, m-half 0; stage A-s0(t+1)
            const u16* pa = paB + aRow0;
#pragma unroll
            for (int f = 0; f < MH; ++f) af[f] = *(const bf16x8*)(pa + f*512);
            const u16* pb = pbB + bRow;
#pragma unroll
            for (int j = 0; j < 4; ++j) wf[j] = *(const bf16x8*)(pb + j*512);
#pragma unroll
            for (int i = 0; i < ICA; ++i) gload_lds16(asrc[0][i] + kpre, sA + adst[0][i] + qa);
            __builtin_amdgcn_s_setprio(1);
#pragma unroll
            for (int f = 0; f < MH; ++f)
#pragma unroll
                for (int j = 0; j < 4; ++j)
                    acc[f][j] = __builtin_amdgcn_mfma_f32_16x16x32_bf16(af[f], wf[j], acc[f][j], 0, 0, 0);
            __builtin_amdgcn_s_setprio(0);
        }
        {   // phase 1: slice 0, m-half 1 (reuses wf); stage B-s0(t+1)
            const u16* pa = paB + aRow0 + MH*512;
#pragma unroll
            for (int f = 0; f < MH; ++f) af[f] = *(const bf16x8*)(pa + f*512);
#pragma unroll
            for (int i = 0; i < ICB; ++i) gload_lds16(bsrc[0][i] + kpre, sB + bdst[0][i] + qb);
            __builtin_amdgcn_s_setprio(1);
#pragma unroll
            for (int f = 0; f < MH; ++f)
#pragma unroll
                for (int j = 0; j < 4; ++j)
                    acc[MH+f][j] = __builtin_amdgcn_mfma_f32_16x16x32_bf16(af[f], wf[j], acc[MH+f][j], 0, 0, 0);
            __builtin_amdgcn_s_setprio(0);
        }
        WAITBAR();   // drains s1(t); s0(t+1) stays in flight
        {   // phase 2: slice 1, m-half 0; stage A-s1(t+1)
            const u16* pa = paB + ASZ + aRow0;
#pragma unroll
            for (int f = 0; f < MH; ++f) af[f] = *(const bf16x8*)(pa + f*512);
            const u16* pb = pbB + BSZ + bRow;
#pragma unroll
            for (int j = 0; j < 4; ++j) wf[j] = *(const bf16x8*)(pb + j*512);
#pragma unroll
            for (int i = 0; i < ICA; ++i) gload_lds16(asrc[1][i] + kpre, sA + adst[1][i] + qa);
            __builtin_amdgcn_s_setprio(1);
#pragma unroll
            for (int f = 0; f < MH; ++f)
#pragma unroll
                for (int j = 0; j < 4; ++j)
                    acc[f][j] = __builtin_amdgcn_mfma_f32_16x16x32_bf16(af[f], wf[j], acc[f][j], 0, 0, 0);
            __builtin_amdgcn_s_setprio(0);
        }
        {   // phase 3: slice 1, m-half 1; stage B-s1(t+1)
            const u16* pa = paB + ASZ + aRow0 + MH*512;
#pragma unroll
            for (int f = 0; f < MH; ++f) af[f] = *(const bf16x8*)(pa + f*512);
#pragma unroll
            for (int i = 0; i < ICB; ++i) gload_lds16(bsrc[1][i] + kpre, sB + bdst[1][i] + qb);
            __builtin_amdgcn_s_setprio(1);
#pragma unroll
            for (int f = 0; f < MH; ++f)
#pragma unroll
                for (int j = 0; j < 4; ++j)
                    acc[MH+f][j] = __builtin_amdgcn_mfma_f32_16x16x32_bf16(af[f], wf[j], acc[MH+f][j], 0, 0, 0);
            __builtin_amdgcn_s_setprio(0);
        }
        WAITBAR();   // drains s0(t+1) before next iter reads it
    }
    asm volatile("s_waitcnt vmcnt(0)" ::: "memory");
    __syncthreads();
#undef WAITBAR

    // ---- epilogue v2 ----
    float* ka = (float*)lds;
    float* kb = ka + BN;
    if (tid < BN) {
        int gn = n0 + tid;
        if constexpr (EPI == 0) {
            float mql = (gn < 768) ? 0.125f : 1.f;
            float bias = 0.f;
            if (gn < 768) bias = e0[gn];
            else if (gn >= 1536) bias = e1[gn-1536];
            float sc = e2[gn];
            ka[tid] = sc * mql;
            kb[tid] = (bias * sc + e3[gn]) * mql;
        } else if constexpr (EPI == 4) {
            ka[tid] = 0.f;
            kb[tid] = e0[gn];
        } else {
            float sc = e1[gn];
            ka[tid] = sc;
            kb[tid] = e0[gn]*sc + e2[gn];
        }
    }
    __syncthreads();
    const int rq = (lane >> 4) * 4;
    const int cc = lane & 15;
    float kaj[4], kbj[4];
#pragma unroll
    for (int j = 0; j < 4; ++j) {
        int c = wc*64 + j*16 + cc;
        kaj[j] = ka[c]; kbj[j] = kb[c];
    }
    __syncthreads();   // done reading coeffs; LDS reusable as C-tile

    if constexpr (EPI == 0 || EPI == 4) {
        // bf16 output: full 256 x (264-padded) u16 tile; vectorized 16B stores
        u16* ct = lds;
#pragma unroll
        for (int i = 0; i < MF; ++i) {
#pragma unroll
            for (int j = 0; j < 4; ++j) {
#pragma unroll
                for (int r = 0; r < 4; ++r) {
                    int rowL = wr*64 + i*16 + rq + r;
                    int col  = wc*64 + j*16 + cc;
                    float v = acc[i][j][r];
                    u16 o;
                    if constexpr (EPI == 0) o = f2b(v*kaj[j] + kbj[j]);
                    else                    o = f2b(gelu_f(v + kbj[j]));
                    ct[rowL*264 + col] = o;
                }
            }
        }
        __syncthreads();
        constexpr int ldc = (EPI == 0) ? 2304 : 3072;
        u16* C = (u16*)Cp;
        constexpr int RPS = TH / 32;          // rows per sweep (32 at TH=1024)
#pragma unroll
        for (int sw = 0; sw < 256/RPS; ++sw) {
            int rowL = sw*RPS + (tid >> 5);
            int gm = m0 + rowL;
            if (gm < M) {
                int col0 = (tid & 31) * 8;
                *(uint4*)(C + (size_t)gm*ldc + n0 + col0) =
                    *(const uint4*)(ct + rowL*264 + col0);
            }
        }
    } else {
        // EPI==5 (BN=256, TH=1024): f32 + fused residual, 4 row-quarters 64x260
        float* cf = (float*)lds;
        float* C = (float*)Cp;
#pragma unroll
        for (int h = 0; h < 4; ++h) {
            if (wr == h) {
#pragma unroll
                for (int i = 0; i < MF; ++i) {
#pragma unroll
                    for (int j = 0; j < 4; ++j) {
#pragma unroll
                        for (int r = 0; r < 4; ++r) {
                            int rowH = i*16 + rq + r;
                            int col  = wc*64 + j*16 + cc;
                            cf[rowH*260 + col] = acc[i][j][r]*kaj[j] + kbj[j];
                        }
                    }
                }
            }
            __syncthreads();
            {
                int row = tid >> 4;                 // 0..63
                int gm = m0 + h*64 + row;
                if (gm < M) {
#pragma unroll
                    for (int k = 0; k < 4; ++k) {
                        int col0 = (tid & 15)*4 + k*64;
                        f32x4 v = *(const f32x4*)(cf + row*260 + col0);
                        size_t gidx = (size_t)gm*768 + n0 + col0;
                        f32x4 xv = *(const f32x4*)(ef + gidx);
                        f32x4 g3 = *(const f32x4*)(e3 + n0 + col0);
                        f32x4 o;
#pragma unroll
                        for (int q = 0; q < 4; ++q) o[q] = xv[q] + g3[q]*v[q];
                        *(f32x4*)(C + gidx) = o;
                    }
                }
            }
            __syncthreads();
        }
    }
}

// ======== 128x128 pipelined NT GEMM, 2 blocks/CU (proj only; R5-verified) ========
// EPI: 3=proj->x1(f32, fused residual)
template<int EPI>
__global__ __launch_bounds__(256, 2)
void gemm128p(const u16* __restrict__ A, const u16* __restrict__ W, void* __restrict__ Cp,
              int M, int N, int K, int lda, int ldw,
              const float* __restrict__ e0, const float* __restrict__ e1,
              const float* __restrict__ e2, const float* __restrict__ e3,
              const float* __restrict__ e4, const float* __restrict__ ef)
{
    extern __shared__ u16 lds[];
    constexpr int SWEEP = 2048;
    constexpr int ICA  = 2;
    constexpr int ICB  = 2;
    constexpr int ASZ  = 128 * 32;
    constexpr int BSZ  = 128 * 32;
    constexpr int ABUF = 2 * ASZ;
    constexpr int BBUF = 2 * BSZ;
    constexpr int MF   = 4;
    constexpr int MH   = 2;

    u16* sA = lds;
    u16* sB = lds + 2 * ABUF;

    const int tid  = threadIdx.x;
    const int lane = tid & 63;
    const int wave = tid >> 6;
    const int wr   = wave >> 1;
    const int wc   = wave & 1;
    const int rid  = lane & 15;
    const int kg   = lane >> 4;
    const int m0   = blockIdx.y * 128;
    const int n0   = blockIdx.x * 128;
    const int t8   = tid * 8;

    const u16* asrc[2][ICA]; int adst[2][ICA];
    const u16* bsrc[2][ICB]; int bdst[2][ICB];
#pragma unroll
    for (int s = 0; s < 2; ++s) {
#pragma unroll
        for (int i = 0; i < ICA; ++i) {
            int e = i*SWEEP + t8, r = e >> 5;
            int g = ((e >> 3) & 3) ^ ((r >> 1) & 3);
            int row = m0 + r; if (row > M-1) row = M-1;
            asrc[s][i] = A + (size_t)row*lda + s*32 + g*8;
            adst[s][i] = s*ASZ + e;
        }
#pragma unroll
        for (int i = 0; i < ICB; ++i) {
            int e = i*SWEEP + t8, r = e >> 5;
            int g = ((e >> 3) & 3) ^ ((r >> 1) & 3);
            int col = n0 + r; if (col > N-1) col = N-1;
            bsrc[s][i] = W + (size_t)col*ldw + s*32 + g*8;
            bdst[s][i] = s*BSZ + e;
        }
    }

    const int koA   = (kg ^ ((rid >> 1) & 3)) * 8;
    const int aRow0 = (wr*64 + rid) * 32 + koA;
    const int bRow  = (wc*64 + rid) * 32 + koA;

    f32x4 acc[MF][4];
#pragma unroll
    for (int i = 0; i < MF; ++i)
#pragma unroll
        for (int j = 0; j < 4; ++j) acc[i][j] = (f32x4){0.f,0.f,0.f,0.f};

#define WAITBAR() asm volatile("s_waitcnt vmcnt(4) lgkmcnt(0)\n\ts_barrier" ::: "memory")

#pragma unroll
    for (int i = 0; i < ICA; ++i) gload_lds16(asrc[0][i], sA + adst[0][i]);
#pragma unroll
    for (int i = 0; i < ICB; ++i) gload_lds16(bsrc[0][i], sB + bdst[0][i]);
    asm volatile("" ::: "memory");
#pragma unroll
    for (int i = 0; i < ICA; ++i) gload_lds16(asrc[1][i], sA + adst[1][i]);
#pragma unroll
    for (int i = 0; i < ICB; ++i) gload_lds16(bsrc[1][i], sB + bdst[1][i]);
    WAITBAR();

    const int NT = K >> 6;
    for (int t = 0; t < NT; ++t) {
        const int p  = t & 1;
        const size_t kpre = (size_t)(t + 1) * 64;
        const u16* paB = sA + p * ABUF;
        const u16* pbB = sB + p * BBUF;
        const int  qa  = (p ^ 1) * ABUF;
        const int  qb  = (p ^ 1) * BBUF;
        bf16x8 af[MH], wf[4];

        {
            const u16* pa = paB + aRow0;
#pragma unroll
            for (int f = 0; f < MH; ++f) af[f] = *(const bf16x8*)(pa + f*512);
            const u16* pb = pbB + bRow;
#pragma unroll
            for (int j = 0; j < 4; ++j) wf[j] = *(const bf16x8*)(pb + j*512);
#pragma unroll
            for (int i = 0; i < ICA; ++i) gload_lds16(asrc[0][i] + kpre, sA + adst[0][i] + qa);
            __builtin_amdgcn_s_setprio(1);
#pragma unroll
            for (int f = 0; f < MH; ++f)
#pragma unroll
                for (int j = 0; j < 4; ++j)
                    acc[f][j] = __builtin_amdgcn_mfma_f32_16x16x32_bf16(af[f], wf[j], acc[f][j], 0, 0, 0);
            __builtin_amdgcn_s_setprio(0);
        }
        {
            const u16* pa = paB + aRow0 + MH*512;
#pragma unroll
            for (int f = 0; f < MH; ++f) af[f] = *(const bf16x8*)(pa + f*512);
#pragma unroll
            for (int i = 0; i < ICB; ++i) gload_lds16(bsrc[0][i] + kpre, sB + bdst[0][i] + qb);
            __builtin_amdgcn_s_setprio(1);
#pragma unroll
            for (int f = 0; f < MH; ++f)
#pragma unroll
                for (int j = 0; j < 4; ++j)
                    acc[MH+f][j] = __builtin_amdgcn_mfma_f32_16x16x32_bf16(af[f], wf[j], acc[MH+f][j], 0, 0, 0);
            __builtin_amdgcn_s_setprio(0);
        }
        WAITBAR();
        {
            const u16* pa = paB + ASZ + aRow0;
#pragma unroll
            for (int f = 0; f < MH; ++f) af[f] = *(const bf16x8*)(pa + f*512);
            const u16* pb = pbB + BSZ + bRow;
#pragma unroll
            for (int j = 0; j < 4; ++j) wf[j] = *(const bf16x8*)(pb + j*512);
#pragma unroll
            for (int i = 0; i < ICA; ++i) gload_lds16(asrc[1][i] + kpre, sA + adst[1][i] + qa);
            __builtin_amdgcn_s_setprio(1);
#pragma unroll
            for (int f = 0; f < MH; ++f)
#pragma unroll
                for (int j = 0; j < 4; ++j)
                    acc[f][j] = __builtin_amdgcn_mfma_f32_16x16x32_bf16(af[f], wf[j], acc[f][j], 0, 0, 0);
            __builtin_amdgcn_s_setprio(0);
        }
        {
            const u16* pa = paB + ASZ + aRow0 + MH*512;
#pragma unroll
            for (int f = 0; f < MH; ++f) af[f] = *(const bf16x8*)(pa + f*512);
#pragma unroll
            for (int i = 0; i < ICB; ++i) gload_lds16(bsrc[1][i] + kpre, sB + bdst[1][i] + qb);
            __builtin_amdgcn_s_setprio(1);
#pragma unroll
            for (int f = 0; f < MH; ++f)
#pragma unroll
                for (int j = 0; j < 4; ++j)
                    acc[MH+f][j] = __builtin_amdgcn_mfma_f32_16x16x32_bf16(af[f], wf[j], acc[MH+f][j], 0, 0, 0);
            __builtin_amdgcn_s_setprio(0);
        }
        WAITBAR();
    }
    asm volatile("s_waitcnt vmcnt(0)" ::: "memory");
    __syncthreads();
#undef WAITBAR

    float* ka = (float*)lds;
    float* kb = ka + 128;
    if (tid < 128) {
        int gn = n0 + tid;
        float sc = e1[gn];
        ka[tid] = sc;
        kb[tid] = e0[gn]*sc + e2[gn];
    }
    __syncthreads();
    const int rq = (lane >> 4) * 4;
    const int cc = lane & 15;
    float kaj[4], kbj[4];
#pragma unroll
    for (int j = 0; j < 4; ++j) {
        int c = wc*64 + j*16 + cc;
        kaj[j] = ka[c]; kbj[j] = kb[c];
    }
    __syncthreads();

    float* cf = (float*)lds;
    const float* RES = e4;
    float* C = (float*)Cp;
#pragma unroll
    for (int h = 0; h < 2; ++h) {
        if (wr == h) {
#pragma unroll
            for (int i = 0; i < MF; ++i) {
#pragma unroll
                for (int j = 0; j < 4; ++j) {
#pragma unroll
                    for (int r = 0; r < 4; ++r) {
                        int rowH = i*16 + rq + r;
                        int col  = wc*64 + j*16 + cc;
                        cf[rowH*132 + col] = acc[i][j][r]*kaj[j] + kbj[j];
                    }
                }
            }
        }
        __syncthreads();
#pragma unroll
        for (int sw = 0; sw < 8; ++sw) {
            int rowH = sw*8 + (tid >> 5);
            int gm = m0 + h*64 + rowH;
            if (gm < M) {
                int col0 = (tid & 31) * 4;
                f32x4 v  = *(const f32x4*)(cf + rowH*132 + col0);
                size_t gidx = (size_t)gm*768 + n0 + col0;
                f32x4 xv = *(const f32x4*)(RES + gidx);
                f32x4 g3 = *(const f32x4*)(e3 + n0 + col0);
                f32x4 o;
#pragma unroll
                for (int q = 0; q < 4; ++q) o[q] = xv[q] + g3[q]*v[q];
                *(f32x4*)(C + gidx) = o;
            }
        }
        __syncthreads();
    }
}

// ======== direct-load NT GEMM for small-K attention GEMMs ========
// EPI: 1=scores (f32 tile staged, bias fused in coalesced sweep)
//      2=pv->y  (V transposed in-kernel into XOR-swizzled LDS; u16 tile staged out)
template<int EPI>
__global__ __launch_bounds__(256)
void gemm_nt(const u16* __restrict__ A, const u16* __restrict__ W, void* __restrict__ Cp,
             int M, int N, int K, int lda, int ldw, int b0,
             const float* __restrict__ ef)
{
    __shared__ __align__(16) u16 csm[(EPI == 1) ? 32768 : 16384];
    // EPI2: V tile [64 d][256 m-slots], XOR-block swizzle blk = (m>>3) ^ (d&31)
    __shared__ __align__(16) u16 vsm[(EPI == 2) ? 64*256 : 1];
    const int tid  = threadIdx.x;
    const int lane = tid & 63;
    const int wave = tid >> 6;
    const int z    = blockIdx.z;
    const int m0   = wave*64;              // grid.y == 1 always (M=197)
    const int n0   = blockIdx.x*64;
    const int rid  = lane & 15;
    const int kq   = (lane >> 4) * 8;

    const u16* Ab = A;
    const u16* Wb = W;
    if constexpr (EPI == 1) {
        int bb = z/12, hh = z - bb*12;
        Ab = A + ((size_t)bb*Nn)*2304 + hh*64;          // q (already *0.125)
        Wb = W + ((size_t)bb*Nn)*2304 + 768 + hh*64;    // k
    } else {
        int bb = z/12, hh = z - bb*12;
        Ab = A + (size_t)z*Nn*NPAD;                     // P
        const u16* vsrc = W + ((size_t)bb*Nn)*2304 + 1536 + hh*64;   // v (natural layout)
        // transpose-stage V into swizzled LDS: vsm[d][m] with 16B-block XOR
        for (int e = tid; e < Nn*64; e += 256) {
            int m = e >> 6, d = e & 63;                 // consecutive lanes -> consecutive d (coalesced)
            vsm[d*256 + ((((m >> 3) ^ d) & 31) << 3) + (m & 7)] = vsrc[(size_t)m*2304 + d];
        }
        for (int e = tid; e < 64*32; e += 256) {        // zero pad m in [197,224)
            int d = e & 63; int m = Nn + (e >> 6);
            if (m < NPAD) vsm[d*256 + ((((m >> 3) ^ d) & 31) << 3) + (m & 7)] = 0;
        }
        __syncthreads();
    }

    f32x4 acc[4][4];
#pragma unroll
    for (int i = 0; i < 4; ++i)
#pragma unroll
        for (int j = 0; j < 4; ++j) acc[i][j] = (f32x4){0.f,0.f,0.f,0.f};

    for (int k0 = 0; k0 < K; k0 += 32) {
        bf16x8 af[4], wf[4];
#pragma unroll
        for (int i = 0; i < 4; ++i) {
            int r = m0 + i*16 + rid; if (r > M-1) r = M-1;
            af[i] = *(const bf16x8*)(Ab + (size_t)r*lda + k0 + kq);
        }
#pragma unroll
        for (int j = 0; j < 4; ++j) {
            if constexpr (EPI == 1) {
                int c = n0 + j*16 + rid; if (c > N-1) c = N-1;
                wf[j] = *(const bf16x8*)(Wb + (size_t)c*ldw + k0 + kq);
            } else {
                int c = j*16 + rid;                     // d-index 0..63 (n0==0)
                int kb = (k0 + kq) >> 3;
                wf[j] = *(const bf16x8*)(vsm + c*256 + (((kb ^ c) & 31) << 3));
            }
        }
#pragma unroll
        for (int i = 0; i < 4; ++i)
#pragma unroll
            for (int j = 0; j < 4; ++j)
                acc[i][j] = __builtin_amdgcn_mfma_f32_16x16x32_bf16(af[i], wf[j], acc[i][j], 0, 0, 0);
    }

    const int rq = (lane >> 4) * 4;
    const int cc = lane & 15;

    if constexpr (EPI == 1) {
        float* cs = (float*)csm;
#pragma unroll
        for (int i = 0; i < 4; ++i)
#pragma unroll
            for (int j = 0; j < 4; ++j)
#pragma unroll
                for (int r = 0; r < 4; ++r)
                    cs[(m0 + i*16 + rq + r)*64 + j*16 + cc] = acc[i][j][r];
        __syncthreads();
        int hh = z - (z/12)*12;
        const float* bsrc = ef + (size_t)hh*NM;
        u16* P = (u16*)Cp + (size_t)z*Nn*NPAD;
        for (int sw = 0; sw < 13; ++sw) {
            int row = sw*16 + (tid >> 4);
            int col0 = (tid & 15) * 4;
            int gn = n0 + col0;
            if (row < Nn && gn < NPAD) {
                f32x4 v = *(const f32x4*)(cs + row*64 + col0);
                const float* bp = bsrc + (size_t)row*Nn + gn;
                float b0v = bp[0], b1v = bp[1], b2v = bp[2], b3v = bp[3];
                unsigned lo = (unsigned)f2b(v[0]+b0v) | ((unsigned)f2b(v[1]+b1v) << 16);
                unsigned hi = (unsigned)f2b(v[2]+b2v) | ((unsigned)f2b(v[3]+b3v) << 16);
                uint2 pk; pk.x = lo; pk.y = hi;
                *(uint2*)(P + (size_t)row*NPAD + gn) = pk;
            }
        }
    } else {
        u16* cs = csm;
#pragma unroll
        for (int i = 0; i < 4; ++i)
#pragma unroll
            for (int j = 0; j < 4; ++j)
#pragma unroll
                for (int r = 0; r < 4; ++r)
                    cs[(m0 + i*16 + rq + r)*64 + j*16 + cc] = f2b(acc[i][j][r]);
        __syncthreads();
        int bb = z/12, kk = z - bb*12;
        u16* Y = (u16*)Cp + ((size_t)(b0+bb)*Nn)*768 + kk*64;
        for (int sw = 0; sw < 7; ++sw) {
            int row = sw*32 + (tid >> 3);
            if (row < Nn) {
                int col0 = (tid & 7) * 8;
                *(uint4*)(Y + (size_t)row*768 + col0) = *(const uint4*)(cs + row*64 + col0);
            }
        }
    }
}

// ---------------- LayerNorm + affine + SSF: f32 in -> bf16 staging out ----------------
__global__ __launch_bounds__(256)
void ln_ssf(const float* __restrict__ x, const float* __restrict__ w, const float* __restrict__ bb,
            const float* __restrict__ sc, const float* __restrict__ sh, u16* __restrict__ out)
{
    const int row = blockIdx.x, tid = threadIdx.x;
    const float* xr = x + (size_t)row * 768;
    float v[3], s1 = 0.f, s2 = 0.f;
#pragma unroll
    for (int i = 0; i < 3; ++i) {
        float f = xr[tid + i*256];
        v[i] = f; s1 += f; s2 += f*f;
    }
    for (int o = 32; o > 0; o >>= 1) { s1 += __shfl_xor(s1, o); s2 += __shfl_xor(s2, o); }
    __shared__ float r1[4], r2[4];
    int wv = tid >> 6;
    if ((tid & 63) == 0) { r1[wv] = s1; r2[wv] = s2; }
    __syncthreads();
    s1 = r1[0]+r1[1]+r1[2]+r1[3];
    s2 = r2[0]+r2[1]+r2[2]+r2[3];
    float mean = s1 * (1.f/768.f);
    float var  = s2 * (1.f/768.f) - mean*mean;
    float rstd = rsqrtf(fmaxf(var, 0.f) + 1e-5f);
#pragma unroll
    for (int i = 0; i < 3; ++i) {
        int c = tid + i*256;
        float h = (v[i] - mean) * rstd * w[c] + bb[c];
        h = h * sc[c] + sh[c];
        out[(size_t)row*768 + c] = f2b(h);
    }
}

// ---------------- rel-pos bias gather ----------------
__global__ __launch_bounds__(256)
void bias_gather(const int* __restrict__ idx, const float* __restrict__ table, float* __restrict__ biasf)
{
    int t = blockIdx.x*256 + threadIdx.x;
    if (t >= NM) return;
    int id = idx[t];
#pragma unroll
    for (int h = 0; h < 12; ++h)
        biasf[(size_t)h*NM + t] = table[id*12 + h];
}

// ---------------- fused softmax + DCF head mixing (vectorized) ----------------
__global__ __launch_bounds__(256)
void softmax_dcf(u16* __restrict__ P, const float* __restrict__ bases, int nb)
{
    __shared__ float cf[144];
    int tid = threadIdx.x;
    if (tid < 144) {
        int k = tid / 12, h = tid - k*12;
        cf[h*12 + k] = bases[k*12 + h] + (h == k ? 1.f : 0.f);
    }
    __syncthreads();
    int ridx = blockIdx.x*4 + (tid >> 6);
    if (ridx >= nb*Nn) return;
    int lane = tid & 63;
    int m0 = lane * 4;
    int bb = ridx / Nn, n = ridx - bb*Nn;
    const size_t hs = (size_t)Nn*NPAD;
    u16* base = P + ((size_t)bb*12)*hs + (size_t)n*NPAD;

    float e[12][4];
#pragma unroll
    for (int h = 0; h < 12; ++h) {
        float s[4];
        if (m0 < NPAD) {
            uint2 pv = *(const uint2*)(base + h*hs + m0);
            s[0] = b2f((u16)(pv.x & 0xFFFF)); s[1] = b2f((u16)(pv.x >> 16));
            s[2] = b2f((u16)(pv.y & 0xFFFF)); s[3] = b2f((u16)(pv.y >> 16));
        } else { s[0]=s[1]=s[2]=s[3] = -1e30f; }
#pragma unroll
        for (int j = 0; j < 4; ++j) if (m0 + j >= Nn) s[j] = -1e30f;
        float mx = fmaxf(fmaxf(s[0], s[1]), fmaxf(s[2], s[3]));
        for (int o = 32; o > 0; o >>= 1) mx = fmaxf(mx, __shfl_xor(mx, o));
        float sum = 0.f;
#pragma unroll
        for (int j = 0; j < 4; ++j) {
            float ev = __expf(fmaxf(s[j] - mx, -80.f));
            if (m0 + j >= Nn) ev = 0.f;
            e[h][j] = ev; sum += ev;
        }
        for (int o = 32; o > 0; o >>= 1) sum += __shfl_xor(sum, o);
        float inv = 1.f / sum;
#pragma unroll
        for (int j = 0; j < 4; ++j) e[h][j] *= inv;
    }
    if (m0 < NPAD) {
#pragma unroll
        for (int k = 0; k < 12; ++k) {
            float o0 = 0.f, o1 = 0.f, o2 = 0.f, o3 = 0.f;
#pragma unroll
            for (int h = 0; h < 12; ++h) {
                float c = cf[h*12 + k];
                o0 += e[h][0]*c; o1 += e[h][1]*c; o2 += e[h][2]*c; o3 += e[h][3]*c;
            }
            unsigned lo = (unsigned)f2b(o0) | ((unsigned)f2b(o1) << 16);
            unsigned hi = (unsigned)f2b(o2) | ((unsigned)f2b(o3) << 16);
            uint2 pk; pk.x = lo; pk.y = hi;
            *(uint2*)(base + k*hs + m0) = pk;
        }
    }
}

extern "C" void kernel_launch(void* const* d_in, const int* in_sizes, int n_in,
                              void* d_out, int out_size, void* d_ws, size_t ws_size,
                              hipStream_t stream)
{
    const float* x       = (const float*)d_in[0];
    const float* w_qkv   = (const float*)d_in[1];
    const float* q_bias  = (const float*)d_in[2];
    const float* v_bias  = (const float*)d_in[3];
    const float* s_qkv   = (const float*)d_in[4];
    const float* sh_qkv  = (const float*)d_in[5];
    const float* rel_tab = (const float*)d_in[6];
    const float* bases   = (const float*)d_in[7];
    const float* w_proj  = (const float*)d_in[8];
    const float* b_proj  = (const float*)d_in[9];
    const float* s_proj  = (const float*)d_in[10];
    const float* sh_proj = (const float*)d_in[11];
    const float* n1w     = (const float*)d_in[12];
    const float* n1b     = (const float*)d_in[13];
    const float* n2w     = (const float*)d_in[14];
    const float* n2b     = (const float*)d_in[15];
    const float* ss1     = (const float*)d_in[16];
    const float* ssh1    = (const float*)d_in[17];
    const float* ss2     = (const float*)d_in[18];
    const float* ssh2    = (const float*)d_in[19];
    const float* w_fc1   = (const float*)d_in[20];
    const float* b_fc1   = (const float*)d_in[21];
    const float* w_fc2   = (const float*)d_in[22];
    const float* b_fc2   = (const float*)d_in[23];
    const float* s_mlp   = (const float*)d_in[24];
    const float* sh_mlp  = (const float*)d_in[25];
    const float* g1      = (const float*)d_in[26];
    const float* g2      = (const float*)d_in[27];
    const int*   relidx  = (const int*)d_in[28];

    char*  ws   = (char*)d_ws;
    u16*   hbuf = (u16*)(ws + OFF_H);
    float* x1   = (float*)(ws + OFF_X1);
    float* bia  = (float*)(ws + OFF_BIA);
    u16*   wb   = (u16*)(ws + OFF_WB);
    float* out  = (float*)d_out;

    u16* wqkvB = wb + WQKV_E;
    u16* wprjB = wb + WPRJ_E;
    u16* wfc1B = wb + WFC1_E;
    u16* wfc2B = wb + WFC2_E;

    hipFuncSetAttribute(reinterpret_cast<const void*>(&gemmv<0,256,1024>),
                        hipFuncAttributeMaxDynamicSharedMemorySize, 139264);
    hipFuncSetAttribute(reinterpret_cast<const void*>(&gemmv<4,256,1024>),
                        hipFuncAttributeMaxDynamicSharedMemorySize, 139264);
    hipFuncSetAttribute(reinterpret_cast<const void*>(&gemmv<5,256,1024>),
                        hipFuncAttributeMaxDynamicSharedMemorySize, 139264);
    hipFuncSetAttribute(reinterpret_cast<const void*>(&gemm128p<3>),
                        hipFuncAttributeMaxDynamicSharedMemorySize, 65536);

    int nb = 64;
    while (nb > 1 && OFF_CH + (size_t)nb*CHUNK_B > ws_size) nb >>= 1;
    const int nchunk = 64 / nb;
    u16* qkvC = (u16*)(ws + OFF_CH);
    u16* PC   = (u16*)(ws + OFF_CH + (size_t)nb*QKV_B);

    // 0) weight conversion f32 -> bf16
    conv_b16<<<dim3(1728), dim3(256), 0, stream>>>(w_qkv, wqkvB, 442368);
    conv_b16<<<dim3(576),  dim3(256), 0, stream>>>(w_proj, wprjB, 147456);
    conv_b16<<<dim3(2304), dim3(256), 0, stream>>>(w_fc1, wfc1B, 589824);
    conv_b16<<<dim3(2304), dim3(256), 0, stream>>>(w_fc2, wfc2B, 589824);

    // 1) LN1 + SSF
    ln_ssf<<<dim3(ROWS), dim3(256), 0, stream>>>(x, n1w, n1b, ss1, ssh1, hbuf);
    // 2) rel-pos bias gather
    bias_gather<<<dim3(152), dim3(256), 0, stream>>>(relidx, rel_tab, bia);

    // 3) attention, chunked over batches
    for (int c = 0; c < nchunk; ++c) {
        const int b0 = c * nb;
        const int nrows = nb * Nn;
        const int gy = (nrows + 255) / 256;
        gemmv<0,256,1024><<<dim3(9, gy), dim3(1024), 139264, stream>>>(
            hbuf + (size_t)b0*Nn*768, wqkvB, qkvC,
            nrows, 2304, 768, 768, 768, q_bias, v_bias, s_qkv, sh_qkv, nullptr);
        gemm_nt<1><<<dim3(4, 1, nb*12), dim3(256), 0, stream>>>(
            qkvC, qkvC, PC, Nn, Nn, 64, 2304, 2304, 0, bia);
        softmax_dcf<<<dim3((nb*Nn + 3)/4), dim3(256), 0, stream>>>(PC, bases, nb);
        gemm_nt<2><<<dim3(1, 1, nb*12), dim3(256), 0, stream>>>(
            PC, qkvC, hbuf, Nn, 64, NPAD, NPAD, 2304, b0, nullptr);
    }

    // 4) proj + SSF + residual -> x1 (f32)  [128x128, 2 blocks/CU]
    gemm128p<3><<<dim3(6, 99), dim3(256), 65536, stream>>>(
        hbuf, wprjB, x1, ROWS, 768, 768, 768, 768,
        b_proj, s_proj, sh_proj, g1, x, nullptr);
    // 5) LN2 + SSF
    ln_ssf<<<dim3(ROWS), dim3(256), 0, stream>>>(x1, n2w, n2b, ss2, ssh2, hbuf);

    // 6) MLP, row-chunked into the (dead) attention chunk region
    u16* mlpC = qkvC;
    size_t avail = (ws_size > OFF_CH) ? (ws_size - OFF_CH) : (size_t)CHUNK_B;
    int nrM = (int)(avail / (MLPD * 2));
    if (nrM < 1) nrM = 1;
    if (nrM > ROWS) nrM = ROWS;
    for (int r0 = 0; r0 < ROWS; r0 += nrM) {
        int cr = ROWS - r0; if (cr > nrM) cr = nrM;
        int gy = (cr + 255) / 256;
        gemmv<4,256,1024><<<dim3(12, gy), dim3(1024), 139264, stream>>>(
            hbuf + (size_t)r0*768, wfc1B, mlpC, cr, 3072, 768, 768, 768,
            b_fc1, nullptr, nullptr, nullptr, nullptr);
        gemmv<5,256,1024><<<dim3(3, gy), dim3(1024), 139264, stream>>>(
            mlpC, wfc2B, out + (size_t)r0*768, cr, 768, 3072, 3072, 3072,
            b_fc2, s_mlp, sh_mlp, g2, x1 + (size_t)r0*768);
    }
}